// Round 10
// baseline (225.684 us; speedup 1.0000x reference)
//
#include <hip/hip_runtime.h>

#define TTOK 4096
#define DDIM 1024
#define FDIM 512
#define NEXP 8
#define HDIM 256
#define RLORA 64
#define CROWS 14336   // 4096 shared + up to 10240 padded expert rows

using u16 = unsigned short;
using f4v = __attribute__((ext_vector_type(4))) float;
using bfrag = __attribute__((ext_vector_type(8))) short;
using u16x8 = __attribute__((ext_vector_type(8))) unsigned short;

static __device__ __forceinline__ float bf2f(u16 u) {
  union { unsigned int u; float f; } x; x.u = ((unsigned int)u) << 16; return x.f;
}
static __device__ __forceinline__ u16 f2bf(float f) {
  union { float f; unsigned int u; } x; x.f = f;
  unsigned int r = (x.u + 0x7fffu + ((x.u >> 16) & 1u)) >> 16;
  return (u16)r;
}
static __device__ __forceinline__ float fq1(float t, float s) {
  float q = rintf(t / s);
  q = fminf(fmaxf(q, -128.f), 127.f);
  return q * s;
}

// ============ 256x256 BK=64 8-wave dbuf GEMM over gathered token rows ============
struct GemmGArgs {
  const u16* A; const u16* B; u16* C;
  const int* tokmap; const int2* blkmap; const int* nbrow;
};

#define STAGE1(d, kt, h, l) \
  __builtin_amdgcn_global_load_lds( \
    (const __attribute__((address_space(1))) void*)(gs[(h)*2+(l)] + (size_t)(kt)*64), \
    (__attribute__((address_space(3))) void*)&lds[(d)*32768 + (h)*8192 + (tid + (l)*512)*8], \
    16, 0, 0)

template <int MODE>
__global__ __launch_bounds__(512, 2) void gemm256g(GemmGArgs g) {
  const int br = blockIdx.x;
  if (br >= g.nbrow[0]) return;
  const int2 bm = g.blkmap[br];
  const int e = bm.x;
  const int m0 = bm.y;
  const int n0 = blockIdx.y * 256;
  const int tid = threadIdx.x;
  const int lane = tid & 63;
  const int wave = tid >> 6;
  const int wr = wave >> 2;
  const int wc = wave & 3;

  constexpr int K = MODE ? 1024 : 512;
  const u16* Bp = g.B + (size_t)e * (MODE ? 1048576 : 524288);

  __shared__ u16 lds[65536];

  // Swizzle: physical 16B-granule p of row r holds logical granule p^(r&7)
  // (pre-swizzled global source; gload_lds dest linear; readers XOR).
  const u16* gs[8];
#pragma unroll
  for (int h = 0; h < 4; h++)
#pragma unroll
    for (int l = 0; l < 2; l++) {
      const int slot = tid + l * 512;
      const int row = slot >> 3, p = slot & 7;
      const int glog = p ^ (row & 7);
      const u16* basep;
      if (h < 2) {
        const int grow = m0 + h * 128 + row;
        const int t = MODE ? g.tokmap[grow] : grow;
        basep = g.A + (size_t)t * K;
      } else {
        basep = Bp + (size_t)(n0 + (h - 2) * 128 + row) * K;
      }
      gs[h * 2 + l] = basep + glog * 8;
    }

  f4v acc[8][4];
#pragma unroll
  for (int i = 0; i < 8; i++)
#pragma unroll
    for (int j = 0; j < 4; j++) acc[i][j] = (f4v){0.f, 0.f, 0.f, 0.f};

  const int q = lane >> 4;
  const int lx = lane & 7;
  const int l15 = lane & 15;

#pragma unroll
  for (int h = 0; h < 4; h++) { STAGE1(0, 0, h, 0); STAGE1(0, 0, h, 1); }
  __syncthreads();

  constexpr int nt = K >> 6;
  for (int kt = 0; kt < nt; ++kt) {
    const int d = kt & 1;
    const int dn = d ^ 1;
    const bool more = (kt + 1 < nt);
#pragma unroll
    for (int kk = 0; kk < 2; ++kk) {
      if (more) {
        if (kk == 0) { STAGE1(dn, kt + 1, 0, 0); STAGE1(dn, kt + 1, 0, 1);
                       STAGE1(dn, kt + 1, 1, 0); STAGE1(dn, kt + 1, 1, 1); }
        else         { STAGE1(dn, kt + 1, 2, 0); STAGE1(dn, kt + 1, 2, 1);
                       STAGE1(dn, kt + 1, 3, 0); STAGE1(dn, kt + 1, 3, 1); }
      }
      bfrag afr[8], bfr[4];
      const int pa = ((kk * 4 + q) ^ lx) << 3;
      const int abase = d * 32768 + wr * 8192 + l15 * 64 + pa;
#pragma unroll
      for (int mi = 0; mi < 8; mi++) afr[mi] = *(const bfrag*)&lds[abase + mi * 1024];
      const int bbase = d * 32768 + (2 + (wc >> 1)) * 8192 + (((wc & 1) << 6) + l15) * 64 + pa;
#pragma unroll
      for (int ni = 0; ni < 4; ni++) bfr[ni] = *(const bfrag*)&lds[bbase + ni * 1024];
      __builtin_amdgcn_s_setprio(1);
#pragma unroll
      for (int mi = 0; mi < 8; mi++)
#pragma unroll
        for (int ni = 0; ni < 4; ni++)
          acc[mi][ni] = __builtin_amdgcn_mfma_f32_16x16x32_bf16(afr[mi], bfr[ni], acc[mi][ni], 0, 0, 0);
      __builtin_amdgcn_s_setprio(0);
    }
    __syncthreads();
  }

  const int crow0 = m0 + wr * 128 + q * 4;

  if (MODE == 1) {
    // fused h2 epilogue: y3 (wc>=2) -> LDS, y1-waves store h2 = y1*sigmoid(y3)
    float* xlds = (float*)lds;
    const int lrow0 = wr * 128 + q * 4;
    if (wc >= 2) {
      const int lc = (wc - 2) * 64 + l15;
#pragma unroll
      for (int mi = 0; mi < 8; mi++)
#pragma unroll
        for (int ni = 0; ni < 4; ni++)
#pragma unroll
          for (int r = 0; r < 4; r++)
            xlds[(lrow0 + mi * 16 + r) * 128 + lc + ni * 16] = acc[mi][ni][r];
    }
    __syncthreads();
    if (wc < 2) {
      const int lc = wc * 64 + l15;
      const int fbase = (n0 >> 1) + lc;
#pragma unroll
      for (int mi = 0; mi < 8; mi++)
#pragma unroll
        for (int r = 0; r < 4; r++) {
          const int rowg = crow0 + mi * 16 + r;
          const int lr = lrow0 + mi * 16 + r;
#pragma unroll
          for (int ni = 0; ni < 4; ni++) {
            float y1 = acc[mi][ni][r];
            float y3 = xlds[lr * 128 + lc + ni * 16];
            float h = y1 / (1.f + __expf(-y3));
            g.C[(size_t)rowg * FDIM + fbase + ni * 16] = f2bf(h);
          }
        }
    }
  } else {
    const int ccol0 = n0 + wc * 64 + l15;
#pragma unroll
    for (int mi = 0; mi < 8; mi++)
#pragma unroll
      for (int ni = 0; ni < 4; ni++) {
        const int col = ccol0 + ni * 16;
#pragma unroll
        for (int r = 0; r < 4; r++)
          g.C[(size_t)(crow0 + mi * 16 + r) * 1024 + col] = f2bf(acc[mi][ni][r]);
      }
  }
}

// ============ merged LoRA fold (27 tensors): C_bf16 = fq(W_fp32, sW[z]) + A@B^T ============
// z<18: W13 geometry M=512,N=1024 (w1/w3 row-interleaved output); z>=18: W2 M=1024,N=512.
// Epilogue: acc -> LDS [128][136] bf16, then coalesced float4 W read + fq + add + u16x8 store.
struct FoldArgs {
  const u16* A0; const u16* B0;
  const float* Wlist[27];
  u16* C13; u16* C2e;
  const float* sW;
};

__global__ __launch_bounds__(256) void gemm_fold(FoldArgs g) {
  const int z = blockIdx.z;
  const bool is13 = z < 18;
  const int bx = blockIdx.x, by = blockIdx.y;
  if (is13 ? (bx >= 4) : (by >= 4)) return;
  const int N = is13 ? 1024 : 512;
  const int K = 64;
  const u16* Ap = is13 ? g.A0 + (size_t)z * 32768 : g.A0 + 589824 + (size_t)(z - 18) * 65536;
  const u16* Bp = is13 ? g.B0 + (size_t)z * 65536 : g.B0 + 1179648 + (size_t)(z - 18) * 32768;
  const float* Wf = g.Wlist[z];
  u16* Cb; int flag;
  if (is13) {
    const int slot = (z >= 16) ? 8 : (z & 7);
    Cb = g.C13 + (size_t)slot * 1048576;
    flag = (z >= 8 && z < 16) || z == 17 ? 2 : 1;
  } else {
    Cb = g.C2e + (size_t)(z - 18) * 524288;
    flag = 0;
  }
  const float sw = fmaxf(g.sW[z] / 127.f, 1e-8f);

  const int tid = threadIdx.x;
  const int lane = tid & 63;
  const int wave = tid >> 6;
  const int wr = wave >> 1, wc = wave & 1;
  const int m0 = bx * 128, n0 = by * 128;

  __shared__ u16 As[128 * 32];
  __shared__ u16 Bs[128 * 32];
  __shared__ u16 stage[128 * 136];

  const int ldrow = tid >> 2;
  const int swzcol = (((tid & 3) ^ ((tid >> 3) & 3)) << 3);
  const u16* ga = Ap + (size_t)(m0 + ldrow) * K + swzcol;
  const u16* gb = Bp + (size_t)(n0 + ldrow) * K + swzcol;
  const size_t rowstep = (size_t)64 * K;

  f4v acc[4][4];
#pragma unroll
  for (int i = 0; i < 4; i++)
#pragma unroll
    for (int j = 0; j < 4; j++) acc[i][j] = (f4v){0.f, 0.f, 0.f, 0.f};

  const int rbase = lane & 15;
  const int q = lane >> 4;
  const int pg = (q ^ ((rbase >> 1) & 3)) << 3;
  const int arow = (wr << 6) + rbase;
  const int brow = (wc << 6) + rbase;

  for (int kt = 0; kt < K; kt += 32) {
    __builtin_amdgcn_global_load_lds((const __attribute__((address_space(1))) void*)(ga),
        (__attribute__((address_space(3))) void*)&As[tid * 8], 16, 0, 0);
    __builtin_amdgcn_global_load_lds((const __attribute__((address_space(1))) void*)(ga + rowstep),
        (__attribute__((address_space(3))) void*)&As[(256 + tid) * 8], 16, 0, 0);
    __builtin_amdgcn_global_load_lds((const __attribute__((address_space(1))) void*)(gb),
        (__attribute__((address_space(3))) void*)&Bs[tid * 8], 16, 0, 0);
    __builtin_amdgcn_global_load_lds((const __attribute__((address_space(1))) void*)(gb + rowstep),
        (__attribute__((address_space(3))) void*)&Bs[(256 + tid) * 8], 16, 0, 0);
    ga += 32; gb += 32;
    __syncthreads();
    bfrag af[4], bf[4];
#pragma unroll
    for (int mi = 0; mi < 4; mi++)
      af[mi] = *(const bfrag*)&As[(arow + mi * 16) * 32 + pg];
#pragma unroll
    for (int ni = 0; ni < 4; ni++)
      bf[ni] = *(const bfrag*)&Bs[(brow + ni * 16) * 32 + pg];
#pragma unroll
    for (int mi = 0; mi < 4; mi++)
#pragma unroll
      for (int ni = 0; ni < 4; ni++)
        acc[mi][ni] = __builtin_amdgcn_mfma_f32_16x16x32_bf16(af[mi], bf[ni], acc[mi][ni], 0, 0, 0);
    __syncthreads();
  }

  // acc -> LDS (bf16, padded row 136)
  const int lrow0 = (wr << 6) + ((lane >> 4) << 2);
  const int lcol0 = (wc << 6) + (lane & 15);
#pragma unroll
  for (int mi = 0; mi < 4; mi++)
#pragma unroll
    for (int ni = 0; ni < 4; ni++) {
      const int n = lcol0 + ni * 16;
#pragma unroll
      for (int r = 0; r < 4; r++)
        stage[(lrow0 + mi * 16 + r) * 136 + n] = f2bf(acc[mi][ni][r]);
    }
  __syncthreads();

  // coalesced pass: 2048 ushort8 slots (128 rows x 16 slots), W read in fp32
  const int dm0 = flag ? (((m0 >> 7) << 8) + (flag == 2 ? 128 : 0)) : m0;
#pragma unroll
  for (int j = 0; j < 8; j++) {
    const int s = j * 256 + tid;
    const int lr = s >> 4;
    const int n8 = (s & 15) << 3;
    const float4 w0 = *(const float4*)&Wf[(size_t)(m0 + lr) * N + n0 + n8];
    const float4 w1 = *(const float4*)&Wf[(size_t)(m0 + lr) * N + n0 + n8 + 4];
    const bfrag sv = *(const bfrag*)&stage[lr * 136 + n8];
    const float wa[8] = {w0.x, w0.y, w0.z, w0.w, w1.x, w1.y, w1.z, w1.w};
    u16x8 o;
#pragma unroll
    for (int k = 0; k < 8; k++)
      o[k] = f2bf(fq1(wa[k], sw) + bf2f((u16)sv[k]));
    *(u16x8*)&Cb[(size_t)(dm0 + lr) * N + n0 + n8] = o;
  }
}

// ============ 128x128 BK=32 GEMM (router hidden): C = relu(A@B^T + bias) ============
struct Gemm128Args { const u16* A; const u16* B; u16* Cb; int N, K; const float* bias; };
__global__ __launch_bounds__(256) void gemm128(Gemm128Args g) {
  const int tid = threadIdx.x;
  const int lane = tid & 63;
  const int wave = tid >> 6;
  const int wr = wave >> 1, wc = wave & 1;
  const int m0 = blockIdx.x * 128, n0 = blockIdx.y * 128;
  const int K = g.K, N = g.N;

  __shared__ u16 As[128 * 32];
  __shared__ u16 Bs[128 * 32];

  const int ldrow = tid >> 2;
  const int swzcol = (((tid & 3) ^ ((tid >> 3) & 3)) << 3);
  const u16* ga = g.A + (size_t)(m0 + ldrow) * K + swzcol;
  const u16* gb = g.B + (size_t)(n0 + ldrow) * K + swzcol;
  const size_t rowstep = (size_t)64 * K;

  f4v acc[4][4];
#pragma unroll
  for (int i = 0; i < 4; i++)
#pragma unroll
    for (int j = 0; j < 4; j++) acc[i][j] = (f4v){0.f, 0.f, 0.f, 0.f};

  const int rbase = lane & 15;
  const int q = lane >> 4;
  const int pg = (q ^ ((rbase >> 1) & 3)) << 3;
  const int arow = (wr << 6) + rbase;
  const int brow = (wc << 6) + rbase;

  for (int kt = 0; kt < K; kt += 32) {
    __builtin_amdgcn_global_load_lds((const __attribute__((address_space(1))) void*)(ga),
        (__attribute__((address_space(3))) void*)&As[tid * 8], 16, 0, 0);
    __builtin_amdgcn_global_load_lds((const __attribute__((address_space(1))) void*)(ga + rowstep),
        (__attribute__((address_space(3))) void*)&As[(256 + tid) * 8], 16, 0, 0);
    __builtin_amdgcn_global_load_lds((const __attribute__((address_space(1))) void*)(gb),
        (__attribute__((address_space(3))) void*)&Bs[tid * 8], 16, 0, 0);
    __builtin_amdgcn_global_load_lds((const __attribute__((address_space(1))) void*)(gb + rowstep),
        (__attribute__((address_space(3))) void*)&Bs[(256 + tid) * 8], 16, 0, 0);
    ga += 32; gb += 32;
    __syncthreads();
    bfrag af[4], bf[4];
#pragma unroll
    for (int mi = 0; mi < 4; mi++)
      af[mi] = *(const bfrag*)&As[(arow + mi * 16) * 32 + pg];
#pragma unroll
    for (int ni = 0; ni < 4; ni++)
      bf[ni] = *(const bfrag*)&Bs[(brow + ni * 16) * 32 + pg];
#pragma unroll
    for (int mi = 0; mi < 4; mi++)
#pragma unroll
      for (int ni = 0; ni < 4; ni++)
        acc[mi][ni] = __builtin_amdgcn_mfma_f32_16x16x32_bf16(af[mi], bf[ni], acc[mi][ni], 0, 0, 0);
    __syncthreads();
  }

  const int crow0 = m0 + (wr << 6) + ((lane >> 4) << 2);
  const int ccol0 = n0 + (wc << 6) + (lane & 15);
#pragma unroll
  for (int mi = 0; mi < 4; mi++)
#pragma unroll
    for (int ni = 0; ni < 4; ni++) {
      const int n = ccol0 + ni * 16;
      const float b = g.bias[n];
#pragma unroll
      for (int r = 0; r < 4; r++) {
        float v = fmaxf(acc[mi][ni][r] + b, 0.f);
        g.Cb[(size_t)(crow0 + mi * 16 + r) * N + n] = f2bf(v);
      }
    }
}

// ---------------- prep: W amax (y<27) + all conversions (y>=27), one launch ----------------
struct PrepArgs {
  const float* W[27]; float* amax;
  const float* xf; u16* xfb;
  const float* p1w; u16* p1wb;
  const float* Asrc[27]; u16* Adst;
  const float* Bsrc[27]; u16* Bdst;
};
__global__ __launch_bounds__(256) void prep_kernel(PrepArgs a) {
  const int y = blockIdx.y;
  const int g0 = blockIdx.x * 256 + threadIdx.x;
  const int stride = gridDim.x * 256;
  if (y < 27) {
    const float4* src = (const float4*)a.W[y];
    float lmax = 0.f;
    for (int i = g0; i < 131072; i += stride) {
      float4 v = src[i];
      lmax = fmaxf(lmax, fmaxf(fmaxf(fabsf(v.x), fabsf(v.y)), fmaxf(fabsf(v.z), fabsf(v.w))));
    }
#pragma unroll
    for (int off = 32; off > 0; off >>= 1) lmax = fmaxf(lmax, __shfl_xor(lmax, off));
    __shared__ float wm[4];
    if ((threadIdx.x & 63) == 0) wm[threadIdx.x >> 6] = lmax;
    __syncthreads();
    if (threadIdx.x == 0) {
      float m = fmaxf(fmaxf(wm[0], wm[1]), fmaxf(wm[2], wm[3]));
      atomicMax((unsigned int*)&a.amax[y], __float_as_uint(m));
    }
  } else if (y <= 30) {
    const int qd = y - 27;
    const float4* src = (const float4*)a.xf + (size_t)qd * 262144;
    ushort4* dst = (ushort4*)a.xfb + (size_t)qd * 262144;
    for (int i = g0; i < 262144; i += stride) {
      float4 v = src[i];
      ushort4 o; o.x = f2bf(v.x); o.y = f2bf(v.y); o.z = f2bf(v.z); o.w = f2bf(v.w);
      dst[i] = o;
    }
  } else if (y == 31) {
    for (int i = g0; i < 65536; i += stride) {
      float4 v = ((const float4*)a.p1w)[i];
      ushort4 o; o.x = f2bf(v.x); o.y = f2bf(v.y); o.z = f2bf(v.z); o.w = f2bf(v.w);
      ((ushort4*)a.p1wb)[i] = o;
    }
    for (int i = g0; i < 1179648; i += stride) {
      int t, off;
      if (i < 589824) { t = i >> 15; off = i & 32767; }
      else { int j = i - 589824; t = 18 + (j >> 16); off = j & 65535; }
      a.Adst[i] = f2bf(a.Asrc[t][off]);
    }
  } else {
    for (int i = g0; i < 1474560; i += stride) {
      int t, src;
      if (i < 1179648) { t = i >> 16; int off = i & 65535; src = (off & 63) * 1024 + (off >> 6); }
      else { int j = i - 1179648; t = 18 + (j >> 15); int off = j & 32767; src = (off & 63) * 512 + (off >> 6); }
      a.Bdst[i] = f2bf(a.Bsrc[t][src]);
    }
  }
}

// ---------------- router small: base = xf@scorer^T + b ; pol = ph@p2^T + b ----------------
struct RouterArgs {
  const float* xf; const u16* ph;
  const float* sw; const float* sb;
  const float* p2w; const float* p2b;
  float* base; float* pol;
};
__global__ __launch_bounds__(256) void router_small(RouterArgs a) {
  __shared__ float sw[8][1024];
  __shared__ float p2[8][256];
  const int tid = threadIdx.x;
  {
    const float4* s0 = (const float4*)a.sw;
    float4* d0 = (float4*)&sw[0][0];
    for (int i = tid; i < 2048; i += 256) d0[i] = s0[i];
    const float4* s1 = (const float4*)a.p2w;
    float4* d1 = (float4*)&p2[0][0];
    for (int i = tid; i < 512; i += 256) d1[i] = s1[i];
  }
  __syncthreads();
  const int tl = tid >> 4, s = tid & 15;
  const int token = blockIdx.x * 16 + tl;
  float acc[8] = {0,0,0,0,0,0,0,0}, pacc[8] = {0,0,0,0,0,0,0,0};
  const float4* xrow = (const float4*)(a.xf + (size_t)token * 1024);
  for (int i = 0; i < 16; i++) {
    const int d4 = i * 16 + s;
    float4 xv = xrow[d4];
#pragma unroll
    for (int e = 0; e < 8; e++) {
      float4 wv = ((const float4*)&sw[e][0])[d4];
      acc[e] += xv.x * wv.x + xv.y * wv.y + xv.z * wv.z + xv.w * wv.w;
    }
  }
  const u16* phrow = a.ph + (size_t)token * 256;
  for (int i = 0; i < 16; i++) {
    const int h = i * 16 + s;
    float pv = bf2f(phrow[h]);
#pragma unroll
    for (int e = 0; e < 8; e++) pacc[e] += pv * p2[e][h];
  }
#pragma unroll
  for (int off = 8; off > 0; off >>= 1)
#pragma unroll
    for (int e = 0; e < 8; e++) {
      acc[e] += __shfl_xor(acc[e], off);
      pacc[e] += __shfl_xor(pacc[e], off);
    }
  if (s == 0) {
#pragma unroll
    for (int e = 0; e < 8; e++) {
      a.base[token * 8 + e] = acc[e] + a.sb[e];
      a.pol[token * 8 + e] = pacc[e] + a.p2b[e];
    }
  }
}

// ---------------- router finalize: softmaxes, losses, top-2, counts ----------------
struct FinArgs {
  const float* base; const float* pol;
  float* partials;
  int* idx2; float2* wb; int* cnt;
};
__global__ __launch_bounds__(256) void router_topk(FinArgs a) {
  const int tid = threadIdx.x;
  const int lane = tid & 63, wv = tid >> 6;
  const int token = blockIdx.x * 256 + tid;
  float b[8], p[8];
#pragma unroll
  for (int e = 0; e < 8; e++) { b[e] = a.base[token * 8 + e]; p[e] = a.pol[token * 8 + e]; }
  float pm = p[0];
#pragma unroll
  for (int e = 1; e < 8; e++) pm = fmaxf(pm, p[e]);
  float pe[8], psum = 0.f;
#pragma unroll
  for (int e = 0; e < 8; e++) { pe[e] = expf(p[e] - pm); psum += pe[e]; }
  const float pinv = 1.f / psum;
  float sl[8];
#pragma unroll
  for (int e = 0; e < 8; e++) sl[e] = (b[e] + pe[e] * pinv) * 0.5f;
  float sm = sl[0];
#pragma unroll
  for (int e = 1; e < 8; e++) sm = fmaxf(sm, sl[e]);
  float sc[8], ssum = 0.f;
#pragma unroll
  for (int e = 0; e < 8; e++) { sc[e] = expf(sl[e] - sm); ssum += sc[e]; }
  const float sinv = 1.f / ssum;
  float ent = 0.f;
#pragma unroll
  for (int e = 0; e < 8; e++) { float v = sc[e] * sinv; sc[e] = v; ent -= v * logf(v + 1e-6f); }
  float bm = b[0];
#pragma unroll
  for (int e = 1; e < 8; e++) bm = fmaxf(bm, b[e]);
  float zs = 0.f;
#pragma unroll
  for (int e = 0; e < 8; e++) zs += expf(b[e] - bm);
  const float lse = logf(zs) + bm;
  const float zt = lse * lse;
  float m1 = -1e30f, m2 = -1e30f; int i1 = 0, i2 = 0;
#pragma unroll
  for (int e = 0; e < 8; e++) {
    float v = sc[e];
    if (v > m1) { m2 = m1; i2 = i1; m1 = v; i1 = e; }
    else if (v > m2) { m2 = v; i2 = e; }
  }
  a.idx2[token] = i1 | (i2 << 8);
  a.wb[token] = make_float2(m1, m2);

  __shared__ int hist[8];
  if (tid < 8) hist[tid] = 0;
  __syncthreads();
  atomicAdd(&hist[i1], 1);
  atomicAdd(&hist[i2], 1);
  __syncthreads();
  if (tid < 8) atomicAdd(&a.cnt[tid], hist[tid]);

  // wave-shuffle partials reduction (10 values)
  float vals[10];
  vals[0] = ent; vals[1] = zt;
#pragma unroll
  for (int e = 0; e < 8; e++) vals[2 + e] = 0.f;
  vals[2 + i1] = m1; vals[2 + i2] = m2;
#pragma unroll
  for (int v = 0; v < 10; v++)
#pragma unroll
    for (int off = 32; off > 0; off >>= 1) vals[v] += __shfl_down(vals[v], off);
  __shared__ float wred[4][10];
  if (lane == 0)
#pragma unroll
    for (int v = 0; v < 10; v++) wred[wv][v] = vals[v];
  __syncthreads();
  if (tid < 10)
    a.partials[blockIdx.x * 10 + tid] = wred[0][tid] + wred[1][tid] + wred[2][tid] + wred[3][tid];
}

// ---------------- compaction + setup + losses in one launch (9 blocks) ----------------
// blocks 0..7: deterministic token-order compaction for expert e (off derived
// locally from cnt prefix); zero own pad rows. block 8: shared-row identity
// tokmap + blkmap/nbrow + loss finalize.
__global__ __launch_bounds__(256) void compact_setup(const int* idx2, const int* cnt,
                                                     int2* blkmap, int* nbrow, int* tokmap,
                                                     int* posb, const float* partials, float* tail) {
  const int e = blockIdx.x;
  const int tid = threadIdx.x;
  if (e == 8) {
    if (tid == 0) {
      int o = 0, nb = 16;
      for (int i = 0; i < 16; i++) blkmap[i] = make_int2(8, i * 256);
      for (int ex = 0; ex < 8; ex++) {
        const int nbe = (cnt[ex] + 255) >> 8;
        for (int i = 0; i < nbe; i++) blkmap[nb++] = make_int2(ex, 4096 + o + i * 256);
        o += nbe << 8;
      }
      nbrow[0] = nb;
    } else if (tid == 64) {
      float ent = 0.f, z = 0.f, us[8] = {0,0,0,0,0,0,0,0};
      for (int i = 0; i < 16; i++) {
        ent += partials[i * 10 + 0];
        z += partials[i * 10 + 1];
        for (int ex = 0; ex < 8; ex++) us[ex] += partials[i * 10 + 2 + ex];
      }
      float tot = 0.f;
      for (int ex = 0; ex < 8; ex++) tot += us[ex];
      const float meanu = tot / 8.f;
      float uf[8], mu = 0.f;
      for (int ex = 0; ex < 8; ex++) { uf[ex] = us[ex] / (meanu + 1e-6f); mu += uf[ex]; }
      mu /= 8.f;
      float var = 0.f;
      for (int ex = 0; ex < 8; ex++) { float d = uf[ex] - mu; var += d * d; }
      var /= 7.f;
      const float bl = 0.3f * var - 0.1f * (ent / 4096.f) + 1e-4f * (z / 4096.f);
      for (int ex = 0; ex < 8; ex++) tail[ex] = us[ex];
      tail[8] = bl; tail[9] = 0.f; tail[10] = 0.f;
    }
    for (int t = tid; t < 4096; t += 256) tokmap[t] = t;
    return;
  }
  const int lane = tid & 63, wv = tid >> 6;
  __shared__ int wtot[4];
  __shared__ int carry;
  if (tid == 0) carry = 0;
  __syncthreads();
  int off = 0;
  for (int i = 0; i < e; i++) off += ((cnt[i] + 255) >> 8) << 8;
  const int base = 4096 + off;
  for (int c = 0; c < 16; c++) {
    const int t = c * 256 + tid;
    const int ii = idx2[t];
    const int i1 = ii & 255, i2 = ii >> 8;
    const int flag = (i1 == e || i2 == e) ? 1 : 0;
    const unsigned long long m = __ballot(flag);
    const int pre = __popcll(m & ((1ull << lane) - 1ull));
    if (lane == 63) wtot[wv] = pre + flag;
    __syncthreads();
    int wbase = 0;
    for (int i = 0; i < wv; i++) wbase += wtot[i];
    if (flag) {
      const int row = base + carry + wbase + pre;
      tokmap[row] = t;
      posb[t * 2 + (i2 == e ? 1 : 0)] = row;
    }
    __syncthreads();
    if (tid == 0) carry += wtot[0] + wtot[1] + wtot[2] + wtot[3];
    __syncthreads();
  }
  const int ce = cnt[e];
  const int pend = ((ce + 255) >> 8) << 8;
  for (int r = ce + tid; r < pend; r += 256) tokmap[base + r] = 0;
}

// ---------------- combine: out[t] = y2c[t] + w1*y2c[p1] + w2*y2c[p2] ----------------
__global__ __launch_bounds__(256) void combine_g(const u16* y2c, const int* posb,
                                                 const float2* wb, float* out) {
  const int t = blockIdx.x;
  const int c = threadIdx.x;
  const float2 w = wb[t];
  const int p1 = posb[t * 2], p2 = posb[t * 2 + 1];
  ushort4 s = ((const ushort4*)(y2c + (size_t)t * 1024))[c];
  ushort4 a = ((const ushort4*)(y2c + (size_t)p1 * 1024))[c];
  ushort4 b = ((const ushort4*)(y2c + (size_t)p2 * 1024))[c];
  float4 o;
  o.x = bf2f(s.x) + w.x * bf2f(a.x) + w.y * bf2f(b.x);
  o.y = bf2f(s.y) + w.x * bf2f(a.y) + w.y * bf2f(b.y);
  o.z = bf2f(s.z) + w.x * bf2f(a.z) + w.y * bf2f(b.z);
  o.w = bf2f(s.w) + w.x * bf2f(a.w) + w.y * bf2f(b.w);
  ((float4*)(out + (size_t)t * 1024))[c] = o;
}

// ---------------- host ----------------
extern "C" void kernel_launch(void* const* d_in, const int* in_sizes, int n_in,
                              void* d_out, int out_size, void* d_ws, size_t ws_size,
                              hipStream_t stream) {
  const float* x = (const float*)d_in[0];
  const float* scorer_w = (const float*)d_in[1];
  const float* scorer_b = (const float*)d_in[2];
  const float* p1_w = (const float*)d_in[3];
  const float* p1_b = (const float*)d_in[4];
  const float* p2_w = (const float*)d_in[5];
  const float* p2_b = (const float*)d_in[6];
  const float* ew1_w = (const float*)d_in[7];
  const float* ew1_a = (const float*)d_in[8];
  const float* ew1_b = (const float*)d_in[9];
  const float* ew2_w = (const float*)d_in[10];
  const float* ew2_a = (const float*)d_in[11];
  const float* ew2_b = (const float*)d_in[12];
  const float* ew3_w = (const float*)d_in[13];
  const float* ew3_a = (const float*)d_in[14];
  const float* ew3_b = (const float*)d_in[15];
  const float* s1_w = (const float*)d_in[16];
  const float* s1_a = (const float*)d_in[17];
  const float* s1_b = (const float*)d_in[18];
  const float* s2_w = (const float*)d_in[19];
  const float* s2_a = (const float*)d_in[20];
  const float* s2_b = (const float*)d_in[21];
  const float* s3_w = (const float*)d_in[22];
  const float* s3_a = (const float*)d_in[23];
  const float* s3_b = (const float*)d_in[24];
  float* outf = (float*)d_out;

  char* w = (char*)d_ws;
  auto alloc = [&](size_t bytes) { char* p = w; w += (bytes + 255) & ~(size_t)255; return p; };
  u16* xfb  = (u16*)alloc((size_t)TTOK * DDIM * 2);
  u16* ph   = (u16*)alloc((size_t)TTOK * HDIM * 2);
  u16* p1wb = (u16*)alloc((size_t)HDIM * DDIM * 2);
  u16* Adst = (u16*)alloc((size_t)1179648 * 2);
  u16* Bdst = (u16*)alloc((size_t)1474560 * 2);
  u16* W13  = (u16*)alloc((size_t)9 * 1024 * 1024 * 2);
  u16* W2e  = (u16*)alloc((size_t)9 * 1024 * 512 * 2);
  u16* h2c  = (u16*)alloc((size_t)CROWS * FDIM * 2);
  u16* y2c  = (u16*)alloc((size_t)CROWS * DDIM * 2);
  float* base = (float*)alloc((size_t)TTOK * 8 * 4);
  float* pol  = (float*)alloc((size_t)TTOK * 8 * 4);
  float* partials = (float*)alloc(16 * 10 * 4);
  float* amaxW = (float*)alloc(27 * 4);   // 256B-aligned slot
  int* cnt    = (int*)alloc(8 * 4);       // next 256B slot (amaxW + 256B)
  int2* blkmap = (int2*)alloc(64 * 8);
  int* nbrow  = (int*)alloc(4);
  int* tokmap = (int*)alloc(CROWS * 4);
  int* posb   = (int*)alloc(TTOK * 2 * 4);
  int* idx2   = (int*)alloc(TTOK * 4);
  float2* wb  = (float2*)alloc(TTOK * 8);

  // amaxW and cnt are adjacent 256B-aligned slots: one memset covers both
  hipMemsetAsync(amaxW, 0, 256 + 8 * 4, stream);

  // 1. prep: W amax + all bf16 conversions, one launch
  {
    PrepArgs a{};
    for (int e = 0; e < 8; e++) {
      a.W[e] = ew1_w + (size_t)e * 524288;
      a.W[8 + e] = ew3_w + (size_t)e * 524288;
      a.W[18 + e] = ew2_w + (size_t)e * 524288;
      a.Asrc[e] = ew1_a + (size_t)e * 32768;
      a.Asrc[8 + e] = ew3_a + (size_t)e * 32768;
      a.Asrc[18 + e] = ew2_a + (size_t)e * 65536;
      a.Bsrc[e] = ew1_b + (size_t)e * 65536;
      a.Bsrc[8 + e] = ew3_b + (size_t)e * 65536;
      a.Bsrc[18 + e] = ew2_b + (size_t)e * 32768;
    }
    a.W[16] = s1_w; a.W[17] = s3_w; a.W[26] = s2_w;
    a.Asrc[16] = s1_a; a.Asrc[17] = s3_a; a.Asrc[26] = s2_a;
    a.Bsrc[16] = s1_b; a.Bsrc[17] = s3_b; a.Bsrc[26] = s2_b;
    a.amax = amaxW;
    a.xf = x; a.xfb = xfb; a.p1w = p1_w; a.p1wb = p1wb;
    a.Adst = Adst; a.Bdst = Bdst;
    hipLaunchKernelGGL(prep_kernel, dim3(64, 33), dim3(256), 0, stream, a);
  }
  // 2. router hidden GEMM (128^2 tile)
  {
    Gemm128Args g{xfb, p1wb, ph, HDIM, DDIM, p1_b};
    hipLaunchKernelGGL(gemm128, dim3(32, 2), dim3(256), 0, stream, g);
  }
  // 3. merged LoRA fold (27 tensors, reads fp32 W, LDS-staged epilogue)
  {
    FoldArgs g{};
    g.A0 = Adst; g.B0 = Bdst; g.C13 = W13; g.C2e = W2e; g.sW = amaxW;
    for (int e = 0; e < 8; e++) {
      g.Wlist[e] = ew1_w + (size_t)e * 524288;
      g.Wlist[8 + e] = ew3_w + (size_t)e * 524288;
      g.Wlist[18 + e] = ew2_w + (size_t)e * 524288;
    }
    g.Wlist[16] = s1_w; g.Wlist[17] = s3_w; g.Wlist[26] = s2_w;
    hipLaunchKernelGGL(gemm_fold, dim3(8, 8, 27), dim3(256), 0, stream, g);
  }
  // 4. router small
  {
    RouterArgs r{};
    r.xf = x; r.ph = ph; r.sw = scorer_w; r.sb = scorer_b;
    r.p2w = p2_w; r.p2b = p2_b; r.base = base; r.pol = pol;
    hipLaunchKernelGGL(router_small, dim3(256), dim3(256), 0, stream, r);
  }
  // 5. router topk + counts
  {
    FinArgs f{base, pol, partials, idx2, wb, cnt};
    hipLaunchKernelGGL(router_topk, dim3(16), dim3(256), 0, stream, f);
  }
  // 6. compaction + setup + losses (9 blocks)
  hipLaunchKernelGGL(compact_setup, dim3(9), dim3(256), 0, stream,
                     idx2, cnt, blkmap, nbrow, tokmap, posb, partials,
                     outf + (size_t)TTOK * DDIM);
  // 7. y13 + fused h2 over gathered rows
  {
    GemmGArgs g{xfb, W13, h2c, tokmap, blkmap, nbrow};
    hipLaunchKernelGGL(gemm256g<1>, dim3(56, 4), dim3(512), 0, stream, g);
  }
  // 8. y2 over concat rows
  {
    GemmGArgs g{h2c, W2e, y2c, tokmap, blkmap, nbrow};
    hipLaunchKernelGGL(gemm256g<0>, dim3(56, 4), dim3(512), 0, stream, g);
  }
  // 9. deterministic combine
  hipLaunchKernelGGL(combine_g, dim3(4096), dim3(256), 0, stream, y2c, posb, wb, outf);
}

// Round 11
// 202.919 us; speedup vs baseline: 1.1122x; 1.1122x over previous
//
#include <hip/hip_runtime.h>

#define TTOK 4096
#define DDIM 1024
#define FDIM 512
#define NEXP 8
#define HDIM 256
#define RLORA 64
#define CROWS 14336   // 4096 shared + up to 10240 padded expert rows

using u16 = unsigned short;
using f4v = __attribute__((ext_vector_type(4))) float;
using bfrag = __attribute__((ext_vector_type(8))) short;
using u16x8 = __attribute__((ext_vector_type(8))) unsigned short;

static __device__ __forceinline__ float bf2f(u16 u) {
  union { unsigned int u; float f; } x; x.u = ((unsigned int)u) << 16; return x.f;
}
static __device__ __forceinline__ u16 f2bf(float f) {
  union { float f; unsigned int u; } x; x.f = f;
  unsigned int r = (x.u + 0x7fffu + ((x.u >> 16) & 1u)) >> 16;
  return (u16)r;
}
static __device__ __forceinline__ float fq1(float t, float s) {
  float q = rintf(t / s);
  q = fminf(fmaxf(q, -128.f), 127.f);
  return q * s;
}

// ============ 256x256 BK=64 8-wave dbuf GEMM over gathered token rows ============
struct GemmGArgs {
  const u16* A; const u16* B; u16* C;
  const int* tokmap; const int2* blkmap; const int* nbrow;
};

#define STAGE1(d, kt, h, l) \
  __builtin_amdgcn_global_load_lds( \
    (const __attribute__((address_space(1))) void*)(gs[(h)*2+(l)] + (size_t)(kt)*64), \
    (__attribute__((address_space(3))) void*)&lds[(d)*32768 + (h)*8192 + (tid + (l)*512)*8], \
    16, 0, 0)

template <int MODE>
__global__ __launch_bounds__(512, 2) void gemm256g(GemmGArgs g) {
  const int br = blockIdx.x;
  if (br >= g.nbrow[0]) return;
  const int2 bm = g.blkmap[br];
  const int e = bm.x;
  const int m0 = bm.y;
  const int n0 = blockIdx.y * 256;
  const int tid = threadIdx.x;
  const int lane = tid & 63;
  const int wave = tid >> 6;
  const int wr = wave >> 2;
  const int wc = wave & 3;

  constexpr int K = MODE ? 1024 : 512;
  const u16* Bp = g.B + (size_t)e * (MODE ? 1048576 : 524288);

  __shared__ u16 lds[65536];

  // Swizzle: physical 16B-granule p of row r holds logical granule p^(r&7)
  // (pre-swizzled global source; gload_lds dest linear; readers XOR).
  const u16* gs[8];
#pragma unroll
  for (int h = 0; h < 4; h++)
#pragma unroll
    for (int l = 0; l < 2; l++) {
      const int slot = tid + l * 512;
      const int row = slot >> 3, p = slot & 7;
      const int glog = p ^ (row & 7);
      const u16* basep;
      if (h < 2) {
        const int grow = m0 + h * 128 + row;
        const int t = MODE ? g.tokmap[grow] : grow;
        basep = g.A + (size_t)t * K;
      } else {
        basep = Bp + (size_t)(n0 + (h - 2) * 128 + row) * K;
      }
      gs[h * 2 + l] = basep + glog * 8;
    }

  f4v acc[8][4];
#pragma unroll
  for (int i = 0; i < 8; i++)
#pragma unroll
    for (int j = 0; j < 4; j++) acc[i][j] = (f4v){0.f, 0.f, 0.f, 0.f};

  const int q = lane >> 4;
  const int lx = lane & 7;
  const int l15 = lane & 15;

#pragma unroll
  for (int h = 0; h < 4; h++) { STAGE1(0, 0, h, 0); STAGE1(0, 0, h, 1); }
  __syncthreads();

  constexpr int nt = K >> 6;
  for (int kt = 0; kt < nt; ++kt) {
    const int d = kt & 1;
    const int dn = d ^ 1;
    const bool more = (kt + 1 < nt);
#pragma unroll
    for (int kk = 0; kk < 2; ++kk) {
      if (more) {
        if (kk == 0) { STAGE1(dn, kt + 1, 0, 0); STAGE1(dn, kt + 1, 0, 1);
                       STAGE1(dn, kt + 1, 1, 0); STAGE1(dn, kt + 1, 1, 1); }
        else         { STAGE1(dn, kt + 1, 2, 0); STAGE1(dn, kt + 1, 2, 1);
                       STAGE1(dn, kt + 1, 3, 0); STAGE1(dn, kt + 1, 3, 1); }
      }
      bfrag afr[8], bfr[4];
      const int pa = ((kk * 4 + q) ^ lx) << 3;
      const int abase = d * 32768 + wr * 8192 + l15 * 64 + pa;
#pragma unroll
      for (int mi = 0; mi < 8; mi++) afr[mi] = *(const bfrag*)&lds[abase + mi * 1024];
      const int bbase = d * 32768 + (2 + (wc >> 1)) * 8192 + (((wc & 1) << 6) + l15) * 64 + pa;
#pragma unroll
      for (int ni = 0; ni < 4; ni++) bfr[ni] = *(const bfrag*)&lds[bbase + ni * 1024];
      __builtin_amdgcn_s_setprio(1);
#pragma unroll
      for (int mi = 0; mi < 8; mi++)
#pragma unroll
        for (int ni = 0; ni < 4; ni++)
          acc[mi][ni] = __builtin_amdgcn_mfma_f32_16x16x32_bf16(afr[mi], bfr[ni], acc[mi][ni], 0, 0, 0);
      __builtin_amdgcn_s_setprio(0);
    }
    __syncthreads();
  }

  const int crow0 = m0 + wr * 128 + q * 4;

  if (MODE == 1) {
    // fused h2 epilogue: y3 (wc>=2) -> LDS, y1-waves store h2 = y1*sigmoid(y3)
    float* xlds = (float*)lds;
    const int lrow0 = wr * 128 + q * 4;
    if (wc >= 2) {
      const int lc = (wc - 2) * 64 + l15;
#pragma unroll
      for (int mi = 0; mi < 8; mi++)
#pragma unroll
        for (int ni = 0; ni < 4; ni++)
#pragma unroll
          for (int r = 0; r < 4; r++)
            xlds[(lrow0 + mi * 16 + r) * 128 + lc + ni * 16] = acc[mi][ni][r];
    }
    __syncthreads();
    if (wc < 2) {
      const int lc = wc * 64 + l15;
      const int fbase = (n0 >> 1) + lc;
#pragma unroll
      for (int mi = 0; mi < 8; mi++)
#pragma unroll
        for (int r = 0; r < 4; r++) {
          const int rowg = crow0 + mi * 16 + r;
          const int lr = lrow0 + mi * 16 + r;
#pragma unroll
          for (int ni = 0; ni < 4; ni++) {
            float y1 = acc[mi][ni][r];
            float y3 = xlds[lr * 128 + lc + ni * 16];
            float h = y1 / (1.f + __expf(-y3));
            g.C[(size_t)rowg * FDIM + fbase + ni * 16] = f2bf(h);
          }
        }
    }
  } else {
    const int ccol0 = n0 + wc * 64 + l15;
#pragma unroll
    for (int mi = 0; mi < 8; mi++)
#pragma unroll
      for (int ni = 0; ni < 4; ni++) {
        const int col = ccol0 + ni * 16;
#pragma unroll
        for (int r = 0; r < 4; r++)
          g.C[(size_t)(crow0 + mi * 16 + r) * 1024 + col] = f2bf(acc[mi][ni][r]);
      }
  }
}

// ============ merged LoRA fold (27 tensors): C_bf16 = fq(W_fp32, sW[z]) + A@B^T ============
// z<18: W13 geometry M=512,N=1024 (w1/w3 row-interleaved output); z>=18: W2 M=1024,N=512.
// Epilogue: acc -> LDS [128][136] bf16, then coalesced float4 W read + fq + add + u16x8 store.
struct FoldArgs {
  const u16* A0; const u16* B0;
  const float* Wlist[27];
  u16* C13; u16* C2e;
  const float* sW;
};

__global__ __launch_bounds__(256) void gemm_fold(FoldArgs g) {
  const int z = blockIdx.z;
  const bool is13 = z < 18;
  const int bx = blockIdx.x, by = blockIdx.y;
  if (is13 ? (bx >= 4) : (by >= 4)) return;
  const int N = is13 ? 1024 : 512;
  const int K = 64;
  const u16* Ap = is13 ? g.A0 + (size_t)z * 32768 : g.A0 + 589824 + (size_t)(z - 18) * 65536;
  const u16* Bp = is13 ? g.B0 + (size_t)z * 65536 : g.B0 + 1179648 + (size_t)(z - 18) * 32768;
  const float* Wf = g.Wlist[z];
  u16* Cb; int flag;
  if (is13) {
    const int slot = (z >= 16) ? 8 : (z & 7);
    Cb = g.C13 + (size_t)slot * 1048576;
    flag = (z >= 8 && z < 16) || z == 17 ? 2 : 1;
  } else {
    Cb = g.C2e + (size_t)(z - 18) * 524288;
    flag = 0;
  }
  const float sw = fmaxf(g.sW[z] / 127.f, 1e-8f);

  const int tid = threadIdx.x;
  const int lane = tid & 63;
  const int wave = tid >> 6;
  const int wr = wave >> 1, wc = wave & 1;
  const int m0 = bx * 128, n0 = by * 128;

  __shared__ u16 As[128 * 32];
  __shared__ u16 Bs[128 * 32];
  __shared__ u16 stage[128 * 136];

  const int ldrow = tid >> 2;
  const int swzcol = (((tid & 3) ^ ((tid >> 3) & 3)) << 3);
  const u16* ga = Ap + (size_t)(m0 + ldrow) * K + swzcol;
  const u16* gb = Bp + (size_t)(n0 + ldrow) * K + swzcol;
  const size_t rowstep = (size_t)64 * K;

  f4v acc[4][4];
#pragma unroll
  for (int i = 0; i < 4; i++)
#pragma unroll
    for (int j = 0; j < 4; j++) acc[i][j] = (f4v){0.f, 0.f, 0.f, 0.f};

  const int rbase = lane & 15;
  const int q = lane >> 4;
  const int pg = (q ^ ((rbase >> 1) & 3)) << 3;
  const int arow = (wr << 6) + rbase;
  const int brow = (wc << 6) + rbase;

  for (int kt = 0; kt < K; kt += 32) {
    __builtin_amdgcn_global_load_lds((const __attribute__((address_space(1))) void*)(ga),
        (__attribute__((address_space(3))) void*)&As[tid * 8], 16, 0, 0);
    __builtin_amdgcn_global_load_lds((const __attribute__((address_space(1))) void*)(ga + rowstep),
        (__attribute__((address_space(3))) void*)&As[(256 + tid) * 8], 16, 0, 0);
    __builtin_amdgcn_global_load_lds((const __attribute__((address_space(1))) void*)(gb),
        (__attribute__((address_space(3))) void*)&Bs[tid * 8], 16, 0, 0);
    __builtin_amdgcn_global_load_lds((const __attribute__((address_space(1))) void*)(gb + rowstep),
        (__attribute__((address_space(3))) void*)&Bs[(256 + tid) * 8], 16, 0, 0);
    ga += 32; gb += 32;
    __syncthreads();
    bfrag af[4], bf[4];
#pragma unroll
    for (int mi = 0; mi < 4; mi++)
      af[mi] = *(const bfrag*)&As[(arow + mi * 16) * 32 + pg];
#pragma unroll
    for (int ni = 0; ni < 4; ni++)
      bf[ni] = *(const bfrag*)&Bs[(brow + ni * 16) * 32 + pg];
#pragma unroll
    for (int mi = 0; mi < 4; mi++)
#pragma unroll
      for (int ni = 0; ni < 4; ni++)
        acc[mi][ni] = __builtin_amdgcn_mfma_f32_16x16x32_bf16(af[mi], bf[ni], acc[mi][ni], 0, 0, 0);
    __syncthreads();
  }

  // acc -> LDS (bf16, padded row 136)
  const int lrow0 = (wr << 6) + ((lane >> 4) << 2);
  const int lcol0 = (wc << 6) + (lane & 15);
#pragma unroll
  for (int mi = 0; mi < 4; mi++)
#pragma unroll
    for (int ni = 0; ni < 4; ni++) {
      const int n = lcol0 + ni * 16;
#pragma unroll
      for (int r = 0; r < 4; r++)
        stage[(lrow0 + mi * 16 + r) * 136 + n] = f2bf(acc[mi][ni][r]);
    }
  __syncthreads();

  // coalesced pass: 2048 ushort8 slots (128 rows x 16 slots), W read in fp32
  const int dm0 = flag ? (((m0 >> 7) << 8) + (flag == 2 ? 128 : 0)) : m0;
#pragma unroll
  for (int j = 0; j < 8; j++) {
    const int s = j * 256 + tid;
    const int lr = s >> 4;
    const int n8 = (s & 15) << 3;
    const float4 w0 = *(const float4*)&Wf[(size_t)(m0 + lr) * N + n0 + n8];
    const float4 w1 = *(const float4*)&Wf[(size_t)(m0 + lr) * N + n0 + n8 + 4];
    const bfrag sv = *(const bfrag*)&stage[lr * 136 + n8];
    const float wa[8] = {w0.x, w0.y, w0.z, w0.w, w1.x, w1.y, w1.z, w1.w};
    u16x8 o;
#pragma unroll
    for (int k = 0; k < 8; k++)
      o[k] = f2bf(fq1(wa[k], sw) + bf2f((u16)sv[k]));
    *(u16x8*)&Cb[(size_t)(dm0 + lr) * N + n0 + n8] = o;
  }
}

// ============ 128x128 BK=32 GEMM (router hidden): C = relu(A@B^T + bias) ============
struct Gemm128Args { const u16* A; const u16* B; u16* Cb; int N, K; const float* bias; };
__global__ __launch_bounds__(256) void gemm128(Gemm128Args g) {
  const int tid = threadIdx.x;
  const int lane = tid & 63;
  const int wave = tid >> 6;
  const int wr = wave >> 1, wc = wave & 1;
  const int m0 = blockIdx.x * 128, n0 = blockIdx.y * 128;
  const int K = g.K, N = g.N;

  __shared__ u16 As[128 * 32];
  __shared__ u16 Bs[128 * 32];

  const int ldrow = tid >> 2;
  const int swzcol = (((tid & 3) ^ ((tid >> 3) & 3)) << 3);
  const u16* ga = g.A + (size_t)(m0 + ldrow) * K + swzcol;
  const u16* gb = g.B + (size_t)(n0 + ldrow) * K + swzcol;
  const size_t rowstep = (size_t)64 * K;

  f4v acc[4][4];
#pragma unroll
  for (int i = 0; i < 4; i++)
#pragma unroll
    for (int j = 0; j < 4; j++) acc[i][j] = (f4v){0.f, 0.f, 0.f, 0.f};

  const int rbase = lane & 15;
  const int q = lane >> 4;
  const int pg = (q ^ ((rbase >> 1) & 3)) << 3;
  const int arow = (wr << 6) + rbase;
  const int brow = (wc << 6) + rbase;

  for (int kt = 0; kt < K; kt += 32) {
    __builtin_amdgcn_global_load_lds((const __attribute__((address_space(1))) void*)(ga),
        (__attribute__((address_space(3))) void*)&As[tid * 8], 16, 0, 0);
    __builtin_amdgcn_global_load_lds((const __attribute__((address_space(1))) void*)(ga + rowstep),
        (__attribute__((address_space(3))) void*)&As[(256 + tid) * 8], 16, 0, 0);
    __builtin_amdgcn_global_load_lds((const __attribute__((address_space(1))) void*)(gb),
        (__attribute__((address_space(3))) void*)&Bs[tid * 8], 16, 0, 0);
    __builtin_amdgcn_global_load_lds((const __attribute__((address_space(1))) void*)(gb + rowstep),
        (__attribute__((address_space(3))) void*)&Bs[(256 + tid) * 8], 16, 0, 0);
    ga += 32; gb += 32;
    __syncthreads();
    bfrag af[4], bf[4];
#pragma unroll
    for (int mi = 0; mi < 4; mi++)
      af[mi] = *(const bfrag*)&As[(arow + mi * 16) * 32 + pg];
#pragma unroll
    for (int ni = 0; ni < 4; ni++)
      bf[ni] = *(const bfrag*)&Bs[(brow + ni * 16) * 32 + pg];
#pragma unroll
    for (int mi = 0; mi < 4; mi++)
#pragma unroll
      for (int ni = 0; ni < 4; ni++)
        acc[mi][ni] = __builtin_amdgcn_mfma_f32_16x16x32_bf16(af[mi], bf[ni], acc[mi][ni], 0, 0, 0);
    __syncthreads();
  }

  const int crow0 = m0 + (wr << 6) + ((lane >> 4) << 2);
  const int ccol0 = n0 + (wc << 6) + (lane & 15);
#pragma unroll
  for (int mi = 0; mi < 4; mi++)
#pragma unroll
    for (int ni = 0; ni < 4; ni++) {
      const int n = ccol0 + ni * 16;
      const float b = g.bias[n];
#pragma unroll
      for (int r = 0; r < 4; r++) {
        float v = fmaxf(acc[mi][ni][r] + b, 0.f);
        g.Cb[(size_t)(crow0 + mi * 16 + r) * N + n] = f2bf(v);
      }
    }
}

// ---------------- W amax only (27 tensors, coalesced 113MB scan) ----------------
struct AmaxArgs { const float* W[27]; float* amax; };
__global__ __launch_bounds__(256) void amax_w_kernel(AmaxArgs a) {
  const int t = blockIdx.y;
  const float4* src = (const float4*)a.W[t];
  float lmax = 0.f;
  for (int i = blockIdx.x * 256 + threadIdx.x; i < 131072; i += gridDim.x * 256) {
    float4 v = src[i];
    lmax = fmaxf(lmax, fmaxf(fmaxf(fabsf(v.x), fabsf(v.y)), fmaxf(fabsf(v.z), fabsf(v.w))));
  }
#pragma unroll
  for (int off = 32; off > 0; off >>= 1) lmax = fmaxf(lmax, __shfl_xor(lmax, off));
  __shared__ float wm[4];
  if ((threadIdx.x & 63) == 0) wm[threadIdx.x >> 6] = lmax;
  __syncthreads();
  if (threadIdx.x == 0) {
    float m = fmaxf(fmaxf(wm[0], wm[1]), fmaxf(wm[2], wm[3]));
    atomicMax((unsigned int*)&a.amax[t], __float_as_uint(m));
  }
}

// ---------------- conversions: x->bf16, p1_w->bf16, loraA->bf16, Bm->Bm^T bf16 ----------------
struct ConvArgs {
  const float* xf; u16* xfb;
  const float* p1w; u16* p1wb;
  const float* Asrc[27]; u16* Adst;
  const float* Bsrc[27]; u16* Bdst;
};
__global__ __launch_bounds__(256) void convert_kernel(ConvArgs a) {
  const int g0 = blockIdx.x * 256 + threadIdx.x;
  const int stride = gridDim.x * 256;
  if (blockIdx.y == 0) {
    for (int i = g0; i < 1048576; i += stride) {
      float4 v = ((const float4*)a.xf)[i];
      ushort4 o; o.x = f2bf(v.x); o.y = f2bf(v.y); o.z = f2bf(v.z); o.w = f2bf(v.w);
      ((ushort4*)a.xfb)[i] = o;
    }
  } else if (blockIdx.y == 1) {
    for (int i = g0; i < 65536; i += stride) {
      float4 v = ((const float4*)a.p1w)[i];
      ushort4 o; o.x = f2bf(v.x); o.y = f2bf(v.y); o.z = f2bf(v.z); o.w = f2bf(v.w);
      ((ushort4*)a.p1wb)[i] = o;
    }
  } else if (blockIdx.y == 2) {
    for (int i = g0; i < 1179648; i += stride) {
      int t, off;
      if (i < 589824) { t = i >> 15; off = i & 32767; }
      else { int j = i - 589824; t = 18 + (j >> 16); off = j & 65535; }
      a.Adst[i] = f2bf(a.Asrc[t][off]);
    }
  } else {
    for (int i = g0; i < 1474560; i += stride) {
      int t, src;
      if (i < 1179648) { t = i >> 16; int off = i & 65535; src = (off & 63) * 1024 + (off >> 6); }
      else { int j = i - 1179648; t = 18 + (j >> 15); int off = j & 32767; src = (off & 63) * 512 + (off >> 6); }
      a.Bdst[i] = f2bf(a.Bsrc[t][src]);
    }
  }
}

// ---------------- router small: base = xf@scorer^T + b ; pol = ph@p2^T + b ----------------
struct RouterArgs {
  const float* xf; const u16* ph;
  const float* sw; const float* sb;
  const float* p2w; const float* p2b;
  float* base; float* pol;
};
__global__ __launch_bounds__(256) void router_small(RouterArgs a) {
  __shared__ float sw[8][1024];
  __shared__ float p2[8][256];
  const int tid = threadIdx.x;
  {
    const float4* s0 = (const float4*)a.sw;
    float4* d0 = (float4*)&sw[0][0];
    for (int i = tid; i < 2048; i += 256) d0[i] = s0[i];
    const float4* s1 = (const float4*)a.p2w;
    float4* d1 = (float4*)&p2[0][0];
    for (int i = tid; i < 512; i += 256) d1[i] = s1[i];
  }
  __syncthreads();
  const int tl = tid >> 4, s = tid & 15;
  const int token = blockIdx.x * 16 + tl;
  float acc[8] = {0,0,0,0,0,0,0,0}, pacc[8] = {0,0,0,0,0,0,0,0};
  const float4* xrow = (const float4*)(a.xf + (size_t)token * 1024);
  for (int i = 0; i < 16; i++) {
    const int d4 = i * 16 + s;
    float4 xv = xrow[d4];
#pragma unroll
    for (int e = 0; e < 8; e++) {
      float4 wv = ((const float4*)&sw[e][0])[d4];
      acc[e] += xv.x * wv.x + xv.y * wv.y + xv.z * wv.z + xv.w * wv.w;
    }
  }
  const u16* phrow = a.ph + (size_t)token * 256;
  for (int i = 0; i < 16; i++) {
    const int h = i * 16 + s;
    float pv = bf2f(phrow[h]);
#pragma unroll
    for (int e = 0; e < 8; e++) pacc[e] += pv * p2[e][h];
  }
#pragma unroll
  for (int off = 8; off > 0; off >>= 1)
#pragma unroll
    for (int e = 0; e < 8; e++) {
      acc[e] += __shfl_xor(acc[e], off);
      pacc[e] += __shfl_xor(pacc[e], off);
    }
  if (s == 0) {
#pragma unroll
    for (int e = 0; e < 8; e++) {
      a.base[token * 8 + e] = acc[e] + a.sb[e];
      a.pol[token * 8 + e] = pacc[e] + a.p2b[e];
    }
  }
}

// ---------------- router finalize: softmaxes, losses, top-2, counts ----------------
struct FinArgs {
  const float* base; const float* pol;
  float* partials;
  int* idx2; float2* wb; int* cnt;
};
__global__ __launch_bounds__(256) void router_topk(FinArgs a) {
  const int tid = threadIdx.x;
  const int lane = tid & 63, wv = tid >> 6;
  const int token = blockIdx.x * 256 + tid;
  float b[8], p[8];
#pragma unroll
  for (int e = 0; e < 8; e++) { b[e] = a.base[token * 8 + e]; p[e] = a.pol[token * 8 + e]; }
  float pm = p[0];
#pragma unroll
  for (int e = 1; e < 8; e++) pm = fmaxf(pm, p[e]);
  float pe[8], psum = 0.f;
#pragma unroll
  for (int e = 0; e < 8; e++) { pe[e] = expf(p[e] - pm); psum += pe[e]; }
  const float pinv = 1.f / psum;
  float sl[8];
#pragma unroll
  for (int e = 0; e < 8; e++) sl[e] = (b[e] + pe[e] * pinv) * 0.5f;
  float sm = sl[0];
#pragma unroll
  for (int e = 1; e < 8; e++) sm = fmaxf(sm, sl[e]);
  float sc[8], ssum = 0.f;
#pragma unroll
  for (int e = 0; e < 8; e++) { sc[e] = expf(sl[e] - sm); ssum += sc[e]; }
  const float sinv = 1.f / ssum;
  float ent = 0.f;
#pragma unroll
  for (int e = 0; e < 8; e++) { float v = sc[e] * sinv; sc[e] = v; ent -= v * logf(v + 1e-6f); }
  float bm = b[0];
#pragma unroll
  for (int e = 1; e < 8; e++) bm = fmaxf(bm, b[e]);
  float zs = 0.f;
#pragma unroll
  for (int e = 0; e < 8; e++) zs += expf(b[e] - bm);
  const float lse = logf(zs) + bm;
  const float zt = lse * lse;
  float m1 = -1e30f, m2 = -1e30f; int i1 = 0, i2 = 0;
#pragma unroll
  for (int e = 0; e < 8; e++) {
    float v = sc[e];
    if (v > m1) { m2 = m1; i2 = i1; m1 = v; i1 = e; }
    else if (v > m2) { m2 = v; i2 = e; }
  }
  a.idx2[token] = i1 | (i2 << 8);
  a.wb[token] = make_float2(m1, m2);

  __shared__ int hist[8];
  if (tid < 8) hist[tid] = 0;
  __syncthreads();
  atomicAdd(&hist[i1], 1);
  atomicAdd(&hist[i2], 1);
  __syncthreads();
  if (tid < 8) atomicAdd(&a.cnt[tid], hist[tid]);

  // wave-shuffle partials reduction (10 values)
  float vals[10];
  vals[0] = ent; vals[1] = zt;
#pragma unroll
  for (int e = 0; e < 8; e++) vals[2 + e] = 0.f;
  vals[2 + i1] = m1; vals[2 + i2] = m2;
#pragma unroll
  for (int v = 0; v < 10; v++)
#pragma unroll
    for (int off = 32; off > 0; off >>= 1) vals[v] += __shfl_down(vals[v], off);
  __shared__ float wred[4][10];
  if (lane == 0)
#pragma unroll
    for (int v = 0; v < 10; v++) wred[wv][v] = vals[v];
  __syncthreads();
  if (tid < 10)
    a.partials[blockIdx.x * 10 + tid] = wred[0][tid] + wred[1][tid] + wred[2][tid] + wred[3][tid];
}

// ---------------- compaction + setup + losses in one launch (9 blocks) ----------------
__global__ __launch_bounds__(256) void compact_setup(const int* idx2, const int* cnt,
                                                     int2* blkmap, int* nbrow, int* tokmap,
                                                     int* posb, const float* partials, float* tail) {
  const int e = blockIdx.x;
  const int tid = threadIdx.x;
  if (e == 8) {
    if (tid == 0) {
      int o = 0, nb = 16;
      for (int i = 0; i < 16; i++) blkmap[i] = make_int2(8, i * 256);
      for (int ex = 0; ex < 8; ex++) {
        const int nbe = (cnt[ex] + 255) >> 8;
        for (int i = 0; i < nbe; i++) blkmap[nb++] = make_int2(ex, 4096 + o + i * 256);
        o += nbe << 8;
      }
      nbrow[0] = nb;
    } else if (tid == 64) {
      float ent = 0.f, z = 0.f, us[8] = {0,0,0,0,0,0,0,0};
      for (int i = 0; i < 16; i++) {
        ent += partials[i * 10 + 0];
        z += partials[i * 10 + 1];
        for (int ex = 0; ex < 8; ex++) us[ex] += partials[i * 10 + 2 + ex];
      }
      float tot = 0.f;
      for (int ex = 0; ex < 8; ex++) tot += us[ex];
      const float meanu = tot / 8.f;
      float uf[8], mu = 0.f;
      for (int ex = 0; ex < 8; ex++) { uf[ex] = us[ex] / (meanu + 1e-6f); mu += uf[ex]; }
      mu /= 8.f;
      float var = 0.f;
      for (int ex = 0; ex < 8; ex++) { float d = uf[ex] - mu; var += d * d; }
      var /= 7.f;
      const float bl = 0.3f * var - 0.1f * (ent / 4096.f) + 1e-4f * (z / 4096.f);
      for (int ex = 0; ex < 8; ex++) tail[ex] = us[ex];
      tail[8] = bl; tail[9] = 0.f; tail[10] = 0.f;
    }
    for (int t = tid; t < 4096; t += 256) tokmap[t] = t;
    return;
  }
  const int lane = tid & 63, wv = tid >> 6;
  __shared__ int wtot[4];
  __shared__ int carry;
  if (tid == 0) carry = 0;
  __syncthreads();
  int off = 0;
  for (int i = 0; i < e; i++) off += ((cnt[i] + 255) >> 8) << 8;
  const int base = 4096 + off;
  for (int c = 0; c < 16; c++) {
    const int t = c * 256 + tid;
    const int ii = idx2[t];
    const int i1 = ii & 255, i2 = ii >> 8;
    const int flag = (i1 == e || i2 == e) ? 1 : 0;
    const unsigned long long m = __ballot(flag);
    const int pre = __popcll(m & ((1ull << lane) - 1ull));
    if (lane == 63) wtot[wv] = pre + flag;
    __syncthreads();
    int wbase = 0;
    for (int i = 0; i < wv; i++) wbase += wtot[i];
    if (flag) {
      const int row = base + carry + wbase + pre;
      tokmap[row] = t;
      posb[t * 2 + (i2 == e ? 1 : 0)] = row;
    }
    __syncthreads();
    if (tid == 0) carry += wtot[0] + wtot[1] + wtot[2] + wtot[3];
    __syncthreads();
  }
  const int ce = cnt[e];
  const int pend = ((ce + 255) >> 8) << 8;
  for (int r = ce + tid; r < pend; r += 256) tokmap[base + r] = 0;
}

// ---------------- combine: out[t] = y2c[t] + w1*y2c[p1] + w2*y2c[p2] ----------------
__global__ __launch_bounds__(256) void combine_g(const u16* y2c, const int* posb,
                                                 const float2* wb, float* out) {
  const int t = blockIdx.x;
  const int c = threadIdx.x;
  const float2 w = wb[t];
  const int p1 = posb[t * 2], p2 = posb[t * 2 + 1];
  ushort4 s = ((const ushort4*)(y2c + (size_t)t * 1024))[c];
  ushort4 a = ((const ushort4*)(y2c + (size_t)p1 * 1024))[c];
  ushort4 b = ((const ushort4*)(y2c + (size_t)p2 * 1024))[c];
  float4 o;
  o.x = bf2f(s.x) + w.x * bf2f(a.x) + w.y * bf2f(b.x);
  o.y = bf2f(s.y) + w.x * bf2f(a.y) + w.y * bf2f(b.y);
  o.z = bf2f(s.z) + w.x * bf2f(a.z) + w.y * bf2f(b.z);
  o.w = bf2f(s.w) + w.x * bf2f(a.w) + w.y * bf2f(b.w);
  ((float4*)(out + (size_t)t * 1024))[c] = o;
}

// ---------------- host ----------------
extern "C" void kernel_launch(void* const* d_in, const int* in_sizes, int n_in,
                              void* d_out, int out_size, void* d_ws, size_t ws_size,
                              hipStream_t stream) {
  const float* x = (const float*)d_in[0];
  const float* scorer_w = (const float*)d_in[1];
  const float* scorer_b = (const float*)d_in[2];
  const float* p1_w = (const float*)d_in[3];
  const float* p1_b = (const float*)d_in[4];
  const float* p2_w = (const float*)d_in[5];
  const float* p2_b = (const float*)d_in[6];
  const float* ew1_w = (const float*)d_in[7];
  const float* ew1_a = (const float*)d_in[8];
  const float* ew1_b = (const float*)d_in[9];
  const float* ew2_w = (const float*)d_in[10];
  const float* ew2_a = (const float*)d_in[11];
  const float* ew2_b = (const float*)d_in[12];
  const float* ew3_w = (const float*)d_in[13];
  const float* ew3_a = (const float*)d_in[14];
  const float* ew3_b = (const float*)d_in[15];
  const float* s1_w = (const float*)d_in[16];
  const float* s1_a = (const float*)d_in[17];
  const float* s1_b = (const float*)d_in[18];
  const float* s2_w = (const float*)d_in[19];
  const float* s2_a = (const float*)d_in[20];
  const float* s2_b = (const float*)d_in[21];
  const float* s3_w = (const float*)d_in[22];
  const float* s3_a = (const float*)d_in[23];
  const float* s3_b = (const float*)d_in[24];
  float* outf = (float*)d_out;

  char* w = (char*)d_ws;
  auto alloc = [&](size_t bytes) { char* p = w; w += (bytes + 255) & ~(size_t)255; return p; };
  u16* xfb  = (u16*)alloc((size_t)TTOK * DDIM * 2);
  u16* ph   = (u16*)alloc((size_t)TTOK * HDIM * 2);
  u16* p1wb = (u16*)alloc((size_t)HDIM * DDIM * 2);
  u16* Adst = (u16*)alloc((size_t)1179648 * 2);
  u16* Bdst = (u16*)alloc((size_t)1474560 * 2);
  u16* W13  = (u16*)alloc((size_t)9 * 1024 * 1024 * 2);
  u16* W2e  = (u16*)alloc((size_t)9 * 1024 * 512 * 2);
  u16* h2c  = (u16*)alloc((size_t)CROWS * FDIM * 2);
  u16* y2c  = (u16*)alloc((size_t)CROWS * DDIM * 2);
  float* base = (float*)alloc((size_t)TTOK * 8 * 4);
  float* pol  = (float*)alloc((size_t)TTOK * 8 * 4);
  float* partials = (float*)alloc(16 * 10 * 4);
  float* amaxW = (float*)alloc(27 * 4);   // 256B-aligned slot
  int* cnt    = (int*)alloc(8 * 4);       // next 256B slot (amaxW + 256B)
  int2* blkmap = (int2*)alloc(64 * 8);
  int* nbrow  = (int*)alloc(4);
  int* tokmap = (int*)alloc(CROWS * 4);
  int* posb   = (int*)alloc(TTOK * 2 * 4);
  int* idx2   = (int*)alloc(TTOK * 4);
  float2* wb  = (float2*)alloc(TTOK * 8);

  // amaxW and cnt are adjacent 256B-aligned slots: one memset covers both
  hipMemsetAsync(amaxW, 0, 256 + 8 * 4, stream);

  // 1. W amax (coalesced scan)
  {
    AmaxArgs a{};
    for (int e = 0; e < 8; e++) {
      a.W[e] = ew1_w + (size_t)e * 524288;
      a.W[8 + e] = ew3_w + (size_t)e * 524288;
      a.W[18 + e] = ew2_w + (size_t)e * 524288;
    }
    a.W[16] = s1_w; a.W[17] = s3_w; a.W[26] = s2_w;
    a.amax = amaxW;
    hipLaunchKernelGGL(amax_w_kernel, dim3(128, 27), dim3(256), 0, stream, a);
  }
  // 2. conversions (load-balanced grid as in R7-R9)
  {
    ConvArgs c{};
    c.xf = x; c.xfb = xfb; c.p1w = p1_w; c.p1wb = p1wb;
    for (int e = 0; e < 8; e++) {
      c.Asrc[e] = ew1_a + (size_t)e * 32768;
      c.Asrc[8 + e] = ew3_a + (size_t)e * 32768;
      c.Asrc[18 + e] = ew2_a + (size_t)e * 65536;
      c.Bsrc[e] = ew1_b + (size_t)e * 65536;
      c.Bsrc[8 + e] = ew3_b + (size_t)e * 65536;
      c.Bsrc[18 + e] = ew2_b + (size_t)e * 32768;
    }
    c.Asrc[16] = s1_a; c.Asrc[17] = s3_a; c.Asrc[26] = s2_a;
    c.Bsrc[16] = s1_b; c.Bsrc[17] = s3_b; c.Bsrc[26] = s2_b;
    c.Adst = Adst; c.Bdst = Bdst;
    hipLaunchKernelGGL(convert_kernel, dim3(1024, 4), dim3(256), 0, stream, c);
  }
  // 3. router hidden GEMM (128^2 tile)
  {
    Gemm128Args g{xfb, p1wb, ph, HDIM, DDIM, p1_b};
    hipLaunchKernelGGL(gemm128, dim3(32, 2), dim3(256), 0, stream, g);
  }
  // 4. merged LoRA fold (27 tensors, reads fp32 W, LDS-staged epilogue)
  {
    FoldArgs g{};
    g.A0 = Adst; g.B0 = Bdst; g.C13 = W13; g.C2e = W2e; g.sW = amaxW;
    for (int e = 0; e < 8; e++) {
      g.Wlist[e] = ew1_w + (size_t)e * 524288;
      g.Wlist[8 + e] = ew3_w + (size_t)e * 524288;
      g.Wlist[18 + e] = ew2_w + (size_t)e * 524288;
    }
    g.Wlist[16] = s1_w; g.Wlist[17] = s3_w; g.Wlist[26] = s2_w;
    hipLaunchKernelGGL(gemm_fold, dim3(8, 8, 27), dim3(256), 0, stream, g);
  }
  // 5. router small
  {
    RouterArgs r{};
    r.xf = x; r.ph = ph; r.sw = scorer_w; r.sb = scorer_b;
    r.p2w = p2_w; r.p2b = p2_b; r.base = base; r.pol = pol;
    hipLaunchKernelGGL(router_small, dim3(256), dim3(256), 0, stream, r);
  }
  // 6. router topk + counts
  {
    FinArgs f{base, pol, partials, idx2, wb, cnt};
    hipLaunchKernelGGL(router_topk, dim3(16), dim3(256), 0, stream, f);
  }
  // 7. compaction + setup + losses (9 blocks)
  hipLaunchKernelGGL(compact_setup, dim3(9), dim3(256), 0, stream,
                     idx2, cnt, blkmap, nbrow, tokmap, posb, partials,
                     outf + (size_t)TTOK * DDIM);
  // 8. y13 + fused h2 over gathered rows
  {
    GemmGArgs g{xfb, W13, h2c, tokmap, blkmap, nbrow};
    hipLaunchKernelGGL(gemm256g<1>, dim3(56, 4), dim3(512), 0, stream, g);
  }
  // 9. y2 over concat rows
  {
    GemmGArgs g{h2c, W2e, y2c, tokmap, blkmap, nbrow};
    hipLaunchKernelGGL(gemm256g<0>, dim3(56, 4), dim3(512), 0, stream, g);
  }
  // 10. deterministic combine
  hipLaunchKernelGGL(combine_g, dim3(4096), dim3(256), 0, stream, y2c, posb, wb, outf);
}

// Round 12
// 202.150 us; speedup vs baseline: 1.1164x; 1.0038x over previous
//
#include <hip/hip_runtime.h>

#define TTOK 4096
#define DDIM 1024
#define FDIM 512
#define NEXP 8
#define HDIM 256
#define RLORA 64
#define CROWS 14336   // 4096 shared + up to 10240 padded expert rows

using u16 = unsigned short;
using f4v = __attribute__((ext_vector_type(4))) float;
using bfrag = __attribute__((ext_vector_type(8))) short;
using u16x8 = __attribute__((ext_vector_type(8))) unsigned short;

static __device__ __forceinline__ float bf2f(u16 u) {
  union { unsigned int u; float f; } x; x.u = ((unsigned int)u) << 16; return x.f;
}
static __device__ __forceinline__ u16 f2bf(float f) {
  union { float f; unsigned int u; } x; x.f = f;
  unsigned int r = (x.u + 0x7fffu + ((x.u >> 16) & 1u)) >> 16;
  return (u16)r;
}
static __device__ __forceinline__ float fq1(float t, float s) {
  float q = rintf(t / s);
  q = fminf(fmaxf(q, -128.f), 127.f);
  return q * s;
}

// ============ 256x256 BK=64 8-wave dbuf GEMM over gathered token rows ============
struct GemmGArgs {
  const u16* A; const u16* B; u16* C;
  const int* tokmap; const int2* blkmap; const int* nbrow;
};

#define STAGE1(d, kt, h, l) \
  __builtin_amdgcn_global_load_lds( \
    (const __attribute__((address_space(1))) void*)(gs[(h)*2+(l)] + (size_t)(kt)*64), \
    (__attribute__((address_space(3))) void*)&lds[(d)*32768 + (h)*8192 + (tid + (l)*512)*8], \
    16, 0, 0)

template <int MODE>
__global__ __launch_bounds__(512, 2) void gemm256g(GemmGArgs g) {
  const int br = blockIdx.x;
  if (br >= g.nbrow[0]) return;
  const int2 bm = g.blkmap[br];
  const int e = bm.x;
  const int m0 = bm.y;
  const int n0 = blockIdx.y * 256;
  const int tid = threadIdx.x;
  const int lane = tid & 63;
  const int wave = tid >> 6;
  const int wr = wave >> 2;
  const int wc = wave & 3;

  constexpr int K = MODE ? 1024 : 512;
  const u16* Bp = g.B + (size_t)e * (MODE ? 1048576 : 524288);

  __shared__ u16 lds[65536];

  // Swizzle: physical 16B-granule p of row r holds logical granule p^(r&7)
  // (pre-swizzled global source; gload_lds dest linear; readers XOR).
  const u16* gs[8];
#pragma unroll
  for (int h = 0; h < 4; h++)
#pragma unroll
    for (int l = 0; l < 2; l++) {
      const int slot = tid + l * 512;
      const int row = slot >> 3, p = slot & 7;
      const int glog = p ^ (row & 7);
      const u16* basep;
      if (h < 2) {
        const int grow = m0 + h * 128 + row;
        const int t = MODE ? g.tokmap[grow] : grow;
        basep = g.A + (size_t)t * K;
      } else {
        basep = Bp + (size_t)(n0 + (h - 2) * 128 + row) * K;
      }
      gs[h * 2 + l] = basep + glog * 8;
    }

  f4v acc[8][4];
#pragma unroll
  for (int i = 0; i < 8; i++)
#pragma unroll
    for (int j = 0; j < 4; j++) acc[i][j] = (f4v){0.f, 0.f, 0.f, 0.f};

  const int q = lane >> 4;
  const int lx = lane & 7;
  const int l15 = lane & 15;

#pragma unroll
  for (int h = 0; h < 4; h++) { STAGE1(0, 0, h, 0); STAGE1(0, 0, h, 1); }
  __syncthreads();

  constexpr int nt = K >> 6;
  for (int kt = 0; kt < nt; ++kt) {
    const int d = kt & 1;
    const int dn = d ^ 1;
    const bool more = (kt + 1 < nt);
#pragma unroll
    for (int kk = 0; kk < 2; ++kk) {
      if (more) {
        if (kk == 0) { STAGE1(dn, kt + 1, 0, 0); STAGE1(dn, kt + 1, 0, 1);
                       STAGE1(dn, kt + 1, 1, 0); STAGE1(dn, kt + 1, 1, 1); }
        else         { STAGE1(dn, kt + 1, 2, 0); STAGE1(dn, kt + 1, 2, 1);
                       STAGE1(dn, kt + 1, 3, 0); STAGE1(dn, kt + 1, 3, 1); }
      }
      bfrag afr[8], bfr[4];
      const int pa = ((kk * 4 + q) ^ lx) << 3;
      const int abase = d * 32768 + wr * 8192 + l15 * 64 + pa;
#pragma unroll
      for (int mi = 0; mi < 8; mi++) afr[mi] = *(const bfrag*)&lds[abase + mi * 1024];
      const int bbase = d * 32768 + (2 + (wc >> 1)) * 8192 + (((wc & 1) << 6) + l15) * 64 + pa;
#pragma unroll
      for (int ni = 0; ni < 4; ni++) bfr[ni] = *(const bfrag*)&lds[bbase + ni * 1024];
      __builtin_amdgcn_s_setprio(1);
#pragma unroll
      for (int mi = 0; mi < 8; mi++)
#pragma unroll
        for (int ni = 0; ni < 4; ni++)
          acc[mi][ni] = __builtin_amdgcn_mfma_f32_16x16x32_bf16(afr[mi], bfr[ni], acc[mi][ni], 0, 0, 0);
      __builtin_amdgcn_s_setprio(0);
    }
    __syncthreads();
  }

  const int crow0 = m0 + wr * 128 + q * 4;

  if (MODE == 1) {
    // fused h2 epilogue: y3 (wc>=2) -> LDS, y1-waves store h2 = y1*sigmoid(y3)
    float* xlds = (float*)lds;
    const int lrow0 = wr * 128 + q * 4;
    if (wc >= 2) {
      const int lc = (wc - 2) * 64 + l15;
#pragma unroll
      for (int mi = 0; mi < 8; mi++)
#pragma unroll
        for (int ni = 0; ni < 4; ni++)
#pragma unroll
          for (int r = 0; r < 4; r++)
            xlds[(lrow0 + mi * 16 + r) * 128 + lc + ni * 16] = acc[mi][ni][r];
    }
    __syncthreads();
    if (wc < 2) {
      const int lc = wc * 64 + l15;
      const int fbase = (n0 >> 1) + lc;
#pragma unroll
      for (int mi = 0; mi < 8; mi++)
#pragma unroll
        for (int r = 0; r < 4; r++) {
          const int rowg = crow0 + mi * 16 + r;
          const int lr = lrow0 + mi * 16 + r;
#pragma unroll
          for (int ni = 0; ni < 4; ni++) {
            float y1 = acc[mi][ni][r];
            float y3 = xlds[lr * 128 + lc + ni * 16];
            float h = y1 / (1.f + __expf(-y3));
            g.C[(size_t)rowg * FDIM + fbase + ni * 16] = f2bf(h);
          }
        }
    }
  } else {
    const int ccol0 = n0 + wc * 64 + l15;
#pragma unroll
    for (int mi = 0; mi < 8; mi++)
#pragma unroll
      for (int ni = 0; ni < 4; ni++) {
        const int col = ccol0 + ni * 16;
#pragma unroll
        for (int r = 0; r < 4; r++)
          g.C[(size_t)(crow0 + mi * 16 + r) * 1024 + col] = f2bf(acc[mi][ni][r]);
      }
  }
}

// ============ merged LoRA fold (27 tensors): C_bf16 = fq(Wraw_bf16, sW[z]) + A@B^T ============
// z<18: W13 geometry M=512,N=1024 (w1/w3 row-interleaved output); z>=18: W2 M=1024,N=512.
// Epilogue: acc -> LDS [128][136] bf16, then coalesced ushort8 pass (R9-proven ~13us).
struct FoldArgs {
  const u16* A0; const u16* B0;
  const u16* Wb;           // bf16 W, tensor z at z*524288
  u16* C13; u16* C2e;
  const float* sW;
};

__global__ __launch_bounds__(256) void gemm_fold(FoldArgs g) {
  const int z = blockIdx.z;
  const bool is13 = z < 18;
  const int bx = blockIdx.x, by = blockIdx.y;
  if (is13 ? (bx >= 4) : (by >= 4)) return;
  const int N = is13 ? 1024 : 512;
  const int K = 64;
  const u16* Ap = is13 ? g.A0 + (size_t)z * 32768 : g.A0 + 589824 + (size_t)(z - 18) * 65536;
  const u16* Bp = is13 ? g.B0 + (size_t)z * 65536 : g.B0 + 1179648 + (size_t)(z - 18) * 32768;
  const u16* Wf = g.Wb + (size_t)z * 524288;
  u16* Cb; int flag;
  if (is13) {
    const int slot = (z >= 16) ? 8 : (z & 7);
    Cb = g.C13 + (size_t)slot * 1048576;
    flag = (z >= 8 && z < 16) || z == 17 ? 2 : 1;
  } else {
    Cb = g.C2e + (size_t)(z - 18) * 524288;
    flag = 0;
  }
  const float sw = fmaxf(g.sW[z] / 127.f, 1e-8f);

  const int tid = threadIdx.x;
  const int lane = tid & 63;
  const int wave = tid >> 6;
  const int wr = wave >> 1, wc = wave & 1;
  const int m0 = bx * 128, n0 = by * 128;

  __shared__ u16 As[128 * 32];
  __shared__ u16 Bs[128 * 32];
  __shared__ u16 stage[128 * 136];

  const int ldrow = tid >> 2;
  const int swzcol = (((tid & 3) ^ ((tid >> 3) & 3)) << 3);
  const u16* ga = Ap + (size_t)(m0 + ldrow) * K + swzcol;
  const u16* gb = Bp + (size_t)(n0 + ldrow) * K + swzcol;
  const size_t rowstep = (size_t)64 * K;

  f4v acc[4][4];
#pragma unroll
  for (int i = 0; i < 4; i++)
#pragma unroll
    for (int j = 0; j < 4; j++) acc[i][j] = (f4v){0.f, 0.f, 0.f, 0.f};

  const int rbase = lane & 15;
  const int q = lane >> 4;
  const int pg = (q ^ ((rbase >> 1) & 3)) << 3;
  const int arow = (wr << 6) + rbase;
  const int brow = (wc << 6) + rbase;

  for (int kt = 0; kt < K; kt += 32) {
    __builtin_amdgcn_global_load_lds((const __attribute__((address_space(1))) void*)(ga),
        (__attribute__((address_space(3))) void*)&As[tid * 8], 16, 0, 0);
    __builtin_amdgcn_global_load_lds((const __attribute__((address_space(1))) void*)(ga + rowstep),
        (__attribute__((address_space(3))) void*)&As[(256 + tid) * 8], 16, 0, 0);
    __builtin_amdgcn_global_load_lds((const __attribute__((address_space(1))) void*)(gb),
        (__attribute__((address_space(3))) void*)&Bs[tid * 8], 16, 0, 0);
    __builtin_amdgcn_global_load_lds((const __attribute__((address_space(1))) void*)(gb + rowstep),
        (__attribute__((address_space(3))) void*)&Bs[(256 + tid) * 8], 16, 0, 0);
    ga += 32; gb += 32;
    __syncthreads();
    bfrag af[4], bf[4];
#pragma unroll
    for (int mi = 0; mi < 4; mi++)
      af[mi] = *(const bfrag*)&As[(arow + mi * 16) * 32 + pg];
#pragma unroll
    for (int ni = 0; ni < 4; ni++)
      bf[ni] = *(const bfrag*)&Bs[(brow + ni * 16) * 32 + pg];
#pragma unroll
    for (int mi = 0; mi < 4; mi++)
#pragma unroll
      for (int ni = 0; ni < 4; ni++)
        acc[mi][ni] = __builtin_amdgcn_mfma_f32_16x16x32_bf16(af[mi], bf[ni], acc[mi][ni], 0, 0, 0);
    __syncthreads();
  }

  // acc -> LDS (bf16, padded row 136)
  const int lrow0 = (wr << 6) + ((lane >> 4) << 2);
  const int lcol0 = (wc << 6) + (lane & 15);
#pragma unroll
  for (int mi = 0; mi < 4; mi++)
#pragma unroll
    for (int ni = 0; ni < 4; ni++) {
      const int n = lcol0 + ni * 16;
#pragma unroll
      for (int r = 0; r < 4; r++)
        stage[(lrow0 + mi * 16 + r) * 136 + n] = f2bf(acc[mi][ni][r]);
    }
  __syncthreads();

  // coalesced pass: 2048 ushort8 slots (128 rows x 16 slots), W read in bf16
  const int dm0 = flag ? (((m0 >> 7) << 8) + (flag == 2 ? 128 : 0)) : m0;
#pragma unroll
  for (int j = 0; j < 8; j++) {
    const int s = j * 256 + tid;
    const int lr = s >> 4;
    const int n8 = (s & 15) << 3;
    const u16x8 wv = *(const u16x8*)&Wf[(size_t)(m0 + lr) * N + n0 + n8];
    const bfrag sv = *(const bfrag*)&stage[lr * 136 + n8];
    u16x8 o;
#pragma unroll
    for (int k = 0; k < 8; k++)
      o[k] = f2bf(fq1(bf2f(wv[k]), sw) + bf2f((u16)sv[k]));
    *(u16x8*)&Cb[(size_t)(dm0 + lr) * N + n0 + n8] = o;
  }
}

// ============ 128x128 BK=32 GEMM (router hidden): C = relu(A@B^T + bias) ============
struct Gemm128Args { const u16* A; const u16* B; u16* Cb; int N, K; const float* bias; };
__global__ __launch_bounds__(256) void gemm128(Gemm128Args g) {
  const int tid = threadIdx.x;
  const int lane = tid & 63;
  const int wave = tid >> 6;
  const int wr = wave >> 1, wc = wave & 1;
  const int m0 = blockIdx.x * 128, n0 = blockIdx.y * 128;
  const int K = g.K, N = g.N;

  __shared__ u16 As[128 * 32];
  __shared__ u16 Bs[128 * 32];

  const int ldrow = tid >> 2;
  const int swzcol = (((tid & 3) ^ ((tid >> 3) & 3)) << 3);
  const u16* ga = g.A + (size_t)(m0 + ldrow) * K + swzcol;
  const u16* gb = g.B + (size_t)(n0 + ldrow) * K + swzcol;
  const size_t rowstep = (size_t)64 * K;

  f4v acc[4][4];
#pragma unroll
  for (int i = 0; i < 4; i++)
#pragma unroll
    for (int j = 0; j < 4; j++) acc[i][j] = (f4v){0.f, 0.f, 0.f, 0.f};

  const int rbase = lane & 15;
  const int q = lane >> 4;
  const int pg = (q ^ ((rbase >> 1) & 3)) << 3;
  const int arow = (wr << 6) + rbase;
  const int brow = (wc << 6) + rbase;

  for (int kt = 0; kt < K; kt += 32) {
    __builtin_amdgcn_global_load_lds((const __attribute__((address_space(1))) void*)(ga),
        (__attribute__((address_space(3))) void*)&As[tid * 8], 16, 0, 0);
    __builtin_amdgcn_global_load_lds((const __attribute__((address_space(1))) void*)(ga + rowstep),
        (__attribute__((address_space(3))) void*)&As[(256 + tid) * 8], 16, 0, 0);
    __builtin_amdgcn_global_load_lds((const __attribute__((address_space(1))) void*)(gb),
        (__attribute__((address_space(3))) void*)&Bs[tid * 8], 16, 0, 0);
    __builtin_amdgcn_global_load_lds((const __attribute__((address_space(1))) void*)(gb + rowstep),
        (__attribute__((address_space(3))) void*)&Bs[(256 + tid) * 8], 16, 0, 0);
    ga += 32; gb += 32;
    __syncthreads();
    bfrag af[4], bf[4];
#pragma unroll
    for (int mi = 0; mi < 4; mi++)
      af[mi] = *(const bfrag*)&As[(arow + mi * 16) * 32 + pg];
#pragma unroll
    for (int ni = 0; ni < 4; ni++)
      bf[ni] = *(const bfrag*)&Bs[(brow + ni * 16) * 32 + pg];
#pragma unroll
    for (int mi = 0; mi < 4; mi++)
#pragma unroll
      for (int ni = 0; ni < 4; ni++)
        acc[mi][ni] = __builtin_amdgcn_mfma_f32_16x16x32_bf16(af[mi], bf[ni], acc[mi][ni], 0, 0, 0);
    __syncthreads();
  }

  const int crow0 = m0 + (wr << 6) + ((lane >> 4) << 2);
  const int ccol0 = n0 + (wc << 6) + (lane & 15);
#pragma unroll
  for (int mi = 0; mi < 4; mi++)
#pragma unroll
    for (int ni = 0; ni < 4; ni++) {
      const int n = ccol0 + ni * 16;
      const float b = g.bias[n];
#pragma unroll
      for (int r = 0; r < 4; r++) {
        float v = fmaxf(acc[mi][ni][r] + b, 0.f);
        g.Cb[(size_t)(crow0 + mi * 16 + r) * N + n] = f2bf(v);
      }
    }
}

// ---------------- amax + W->bf16, 4 independent float4 loads/thread ----------------
struct AmaxCArgs { const float* W[27]; u16* Wraw; float* amax; };
__global__ __launch_bounds__(256) void amax_convw(AmaxCArgs a) {
  const int t = blockIdx.y;
  const float4* src = (const float4*)a.W[t];
  ushort4* dst = (ushort4*)(a.Wraw + (size_t)t * 524288);
  const int i0 = blockIdx.x * 256 + threadIdx.x;   // grid.x = 128 -> 32768 threads/tensor
  float4 v0 = src[i0];
  float4 v1 = src[i0 + 32768];
  float4 v2 = src[i0 + 65536];
  float4 v3 = src[i0 + 98304];
  ushort4 o0, o1, o2, o3;
  o0.x = f2bf(v0.x); o0.y = f2bf(v0.y); o0.z = f2bf(v0.z); o0.w = f2bf(v0.w);
  o1.x = f2bf(v1.x); o1.y = f2bf(v1.y); o1.z = f2bf(v1.z); o1.w = f2bf(v1.w);
  o2.x = f2bf(v2.x); o2.y = f2bf(v2.y); o2.z = f2bf(v2.z); o2.w = f2bf(v2.w);
  o3.x = f2bf(v3.x); o3.y = f2bf(v3.y); o3.z = f2bf(v3.z); o3.w = f2bf(v3.w);
  dst[i0] = o0; dst[i0 + 32768] = o1; dst[i0 + 65536] = o2; dst[i0 + 98304] = o3;
  float m01 = fmaxf(fmaxf(fabsf(v0.x), fabsf(v0.y)), fmaxf(fabsf(v0.z), fabsf(v0.w)));
  float m11 = fmaxf(fmaxf(fabsf(v1.x), fabsf(v1.y)), fmaxf(fabsf(v1.z), fabsf(v1.w)));
  float m21 = fmaxf(fmaxf(fabsf(v2.x), fabsf(v2.y)), fmaxf(fabsf(v2.z), fabsf(v2.w)));
  float m31 = fmaxf(fmaxf(fabsf(v3.x), fabsf(v3.y)), fmaxf(fabsf(v3.z), fabsf(v3.w)));
  float lmax = fmaxf(fmaxf(m01, m11), fmaxf(m21, m31));
#pragma unroll
  for (int off = 32; off > 0; off >>= 1) lmax = fmaxf(lmax, __shfl_xor(lmax, off));
  __shared__ float wm[4];
  if ((threadIdx.x & 63) == 0) wm[threadIdx.x >> 6] = lmax;
  __syncthreads();
  if (threadIdx.x == 0) {
    float m = fmaxf(fmaxf(wm[0], wm[1]), fmaxf(wm[2], wm[3]));
    atomicMax((unsigned int*)&a.amax[t], __float_as_uint(m));
  }
}

// ---------------- conversions: x->bf16, p1_w->bf16, loraA->bf16, Bm->Bm^T bf16 ----------------
struct ConvArgs {
  const float* xf; u16* xfb;
  const float* p1w; u16* p1wb;
  const float* Asrc[27]; u16* Adst;
  const float* Bsrc[27]; u16* Bdst;
};
__global__ __launch_bounds__(256) void convert_kernel(ConvArgs a) {
  const int g0 = blockIdx.x * 256 + threadIdx.x;
  const int stride = gridDim.x * 256;
  if (blockIdx.y == 0) {
    for (int i = g0; i < 1048576; i += stride) {
      float4 v = ((const float4*)a.xf)[i];
      ushort4 o; o.x = f2bf(v.x); o.y = f2bf(v.y); o.z = f2bf(v.z); o.w = f2bf(v.w);
      ((ushort4*)a.xfb)[i] = o;
    }
  } else if (blockIdx.y == 1) {
    for (int i = g0; i < 65536; i += stride) {
      float4 v = ((const float4*)a.p1w)[i];
      ushort4 o; o.x = f2bf(v.x); o.y = f2bf(v.y); o.z = f2bf(v.z); o.w = f2bf(v.w);
      ((ushort4*)a.p1wb)[i] = o;
    }
  } else if (blockIdx.y == 2) {
    for (int i = g0; i < 1179648; i += stride) {
      int t, off;
      if (i < 589824) { t = i >> 15; off = i & 32767; }
      else { int j = i - 589824; t = 18 + (j >> 16); off = j & 65535; }
      a.Adst[i] = f2bf(a.Asrc[t][off]);
    }
  } else {
    for (int i = g0; i < 1474560; i += stride) {
      int t, src;
      if (i < 1179648) { t = i >> 16; int off = i & 65535; src = (off & 63) * 1024 + (off >> 6); }
      else { int j = i - 1179648; t = 18 + (j >> 15); int off = j & 32767; src = (off & 63) * 512 + (off >> 6); }
      a.Bdst[i] = f2bf(a.Bsrc[t][src]);
    }
  }
}

// ---------------- router small: base = xf@scorer^T + b ; pol = ph@p2^T + b ----------------
struct RouterArgs {
  const float* xf; const u16* ph;
  const float* sw; const float* sb;
  const float* p2w; const float* p2b;
  float* base; float* pol;
};
__global__ __launch_bounds__(256) void router_small(RouterArgs a) {
  __shared__ float sw[8][1024];
  __shared__ float p2[8][256];
  const int tid = threadIdx.x;
  {
    const float4* s0 = (const float4*)a.sw;
    float4* d0 = (float4*)&sw[0][0];
    for (int i = tid; i < 2048; i += 256) d0[i] = s0[i];
    const float4* s1 = (const float4*)a.p2w;
    float4* d1 = (float4*)&p2[0][0];
    for (int i = tid; i < 512; i += 256) d1[i] = s1[i];
  }
  __syncthreads();
  const int tl = tid >> 4, s = tid & 15;
  const int token = blockIdx.x * 16 + tl;
  float acc[8] = {0,0,0,0,0,0,0,0}, pacc[8] = {0,0,0,0,0,0,0,0};
  const float4* xrow = (const float4*)(a.xf + (size_t)token * 1024);
  for (int i = 0; i < 16; i++) {
    const int d4 = i * 16 + s;
    float4 xv = xrow[d4];
#pragma unroll
    for (int e = 0; e < 8; e++) {
      float4 wv = ((const float4*)&sw[e][0])[d4];
      acc[e] += xv.x * wv.x + xv.y * wv.y + xv.z * wv.z + xv.w * wv.w;
    }
  }
  const u16* phrow = a.ph + (size_t)token * 256;
  for (int i = 0; i < 16; i++) {
    const int h = i * 16 + s;
    float pv = bf2f(phrow[h]);
#pragma unroll
    for (int e = 0; e < 8; e++) pacc[e] += pv * p2[e][h];
  }
#pragma unroll
  for (int off = 8; off > 0; off >>= 1)
#pragma unroll
    for (int e = 0; e < 8; e++) {
      acc[e] += __shfl_xor(acc[e], off);
      pacc[e] += __shfl_xor(pacc[e], off);
    }
  if (s == 0) {
#pragma unroll
    for (int e = 0; e < 8; e++) {
      a.base[token * 8 + e] = acc[e] + a.sb[e];
      a.pol[token * 8 + e] = pacc[e] + a.p2b[e];
    }
  }
}

// ---------------- router finalize: softmaxes, losses, top-2, counts ----------------
struct FinArgs {
  const float* base; const float* pol;
  float* partials;
  int* idx2; float2* wb; int* cnt;
};
__global__ __launch_bounds__(256) void router_topk(FinArgs a) {
  const int tid = threadIdx.x;
  const int lane = tid & 63, wv = tid >> 6;
  const int token = blockIdx.x * 256 + tid;
  float b[8], p[8];
#pragma unroll
  for (int e = 0; e < 8; e++) { b[e] = a.base[token * 8 + e]; p[e] = a.pol[token * 8 + e]; }
  float pm = p[0];
#pragma unroll
  for (int e = 1; e < 8; e++) pm = fmaxf(pm, p[e]);
  float pe[8], psum = 0.f;
#pragma unroll
  for (int e = 0; e < 8; e++) { pe[e] = expf(p[e] - pm); psum += pe[e]; }
  const float pinv = 1.f / psum;
  float sl[8];
#pragma unroll
  for (int e = 0; e < 8; e++) sl[e] = (b[e] + pe[e] * pinv) * 0.5f;
  float sm = sl[0];
#pragma unroll
  for (int e = 1; e < 8; e++) sm = fmaxf(sm, sl[e]);
  float sc[8], ssum = 0.f;
#pragma unroll
  for (int e = 0; e < 8; e++) { sc[e] = expf(sl[e] - sm); ssum += sc[e]; }
  const float sinv = 1.f / ssum;
  float ent = 0.f;
#pragma unroll
  for (int e = 0; e < 8; e++) { float v = sc[e] * sinv; sc[e] = v; ent -= v * logf(v + 1e-6f); }
  float bm = b[0];
#pragma unroll
  for (int e = 1; e < 8; e++) bm = fmaxf(bm, b[e]);
  float zs = 0.f;
#pragma unroll
  for (int e = 0; e < 8; e++) zs += expf(b[e] - bm);
  const float lse = logf(zs) + bm;
  const float zt = lse * lse;
  float m1 = -1e30f, m2 = -1e30f; int i1 = 0, i2 = 0;
#pragma unroll
  for (int e = 0; e < 8; e++) {
    float v = sc[e];
    if (v > m1) { m2 = m1; i2 = i1; m1 = v; i1 = e; }
    else if (v > m2) { m2 = v; i2 = e; }
  }
  a.idx2[token] = i1 | (i2 << 8);
  a.wb[token] = make_float2(m1, m2);

  __shared__ int hist[8];
  if (tid < 8) hist[tid] = 0;
  __syncthreads();
  atomicAdd(&hist[i1], 1);
  atomicAdd(&hist[i2], 1);
  __syncthreads();
  if (tid < 8) atomicAdd(&a.cnt[tid], hist[tid]);

  // wave-shuffle partials reduction (10 values)
  float vals[10];
  vals[0] = ent; vals[1] = zt;
#pragma unroll
  for (int e = 0; e < 8; e++) vals[2 + e] = 0.f;
  vals[2 + i1] = m1; vals[2 + i2] = m2;
#pragma unroll
  for (int v = 0; v < 10; v++)
#pragma unroll
    for (int off = 32; off > 0; off >>= 1) vals[v] += __shfl_down(vals[v], off);
  __shared__ float wred[4][10];
  if (lane == 0)
#pragma unroll
    for (int v = 0; v < 10; v++) wred[wv][v] = vals[v];
  __syncthreads();
  if (tid < 10)
    a.partials[blockIdx.x * 10 + tid] = wred[0][tid] + wred[1][tid] + wred[2][tid] + wred[3][tid];
}

// ---------------- compaction + setup + losses in one launch (9 blocks) ----------------
__global__ __launch_bounds__(256) void compact_setup(const int* idx2, const int* cnt,
                                                     int2* blkmap, int* nbrow, int* tokmap,
                                                     int* posb, const float* partials, float* tail) {
  const int e = blockIdx.x;
  const int tid = threadIdx.x;
  if (e == 8) {
    if (tid == 0) {
      int o = 0, nb = 16;
      for (int i = 0; i < 16; i++) blkmap[i] = make_int2(8, i * 256);
      for (int ex = 0; ex < 8; ex++) {
        const int nbe = (cnt[ex] + 255) >> 8;
        for (int i = 0; i < nbe; i++) blkmap[nb++] = make_int2(ex, 4096 + o + i * 256);
        o += nbe << 8;
      }
      nbrow[0] = nb;
    } else if (tid == 64) {
      float ent = 0.f, z = 0.f, us[8] = {0,0,0,0,0,0,0,0};
      for (int i = 0; i < 16; i++) {
        ent += partials[i * 10 + 0];
        z += partials[i * 10 + 1];
        for (int ex = 0; ex < 8; ex++) us[ex] += partials[i * 10 + 2 + ex];
      }
      float tot = 0.f;
      for (int ex = 0; ex < 8; ex++) tot += us[ex];
      const float meanu = tot / 8.f;
      float uf[8], mu = 0.f;
      for (int ex = 0; ex < 8; ex++) { uf[ex] = us[ex] / (meanu + 1e-6f); mu += uf[ex]; }
      mu /= 8.f;
      float var = 0.f;
      for (int ex = 0; ex < 8; ex++) { float d = uf[ex] - mu; var += d * d; }
      var /= 7.f;
      const float bl = 0.3f * var - 0.1f * (ent / 4096.f) + 1e-4f * (z / 4096.f);
      for (int ex = 0; ex < 8; ex++) tail[ex] = us[ex];
      tail[8] = bl; tail[9] = 0.f; tail[10] = 0.f;
    }
    for (int t = tid; t < 4096; t += 256) tokmap[t] = t;
    return;
  }
  const int lane = tid & 63, wv = tid >> 6;
  __shared__ int wtot[4];
  __shared__ int carry;
  if (tid == 0) carry = 0;
  __syncthreads();
  int off = 0;
  for (int i = 0; i < e; i++) off += ((cnt[i] + 255) >> 8) << 8;
  const int base = 4096 + off;
  for (int c = 0; c < 16; c++) {
    const int t = c * 256 + tid;
    const int ii = idx2[t];
    const int i1 = ii & 255, i2 = ii >> 8;
    const int flag = (i1 == e || i2 == e) ? 1 : 0;
    const unsigned long long m = __ballot(flag);
    const int pre = __popcll(m & ((1ull << lane) - 1ull));
    if (lane == 63) wtot[wv] = pre + flag;
    __syncthreads();
    int wbase = 0;
    for (int i = 0; i < wv; i++) wbase += wtot[i];
    if (flag) {
      const int row = base + carry + wbase + pre;
      tokmap[row] = t;
      posb[t * 2 + (i2 == e ? 1 : 0)] = row;
    }
    __syncthreads();
    if (tid == 0) carry += wtot[0] + wtot[1] + wtot[2] + wtot[3];
    __syncthreads();
  }
  const int ce = cnt[e];
  const int pend = ((ce + 255) >> 8) << 8;
  for (int r = ce + tid; r < pend; r += 256) tokmap[base + r] = 0;
}

// ---------------- combine: out[t] = y2c[t] + w1*y2c[p1] + w2*y2c[p2] ----------------
__global__ __launch_bounds__(256) void combine_g(const u16* y2c, const int* posb,
                                                 const float2* wb, float* out) {
  const int t = blockIdx.x;
  const int c = threadIdx.x;
  const float2 w = wb[t];
  const int p1 = posb[t * 2], p2 = posb[t * 2 + 1];
  ushort4 s = ((const ushort4*)(y2c + (size_t)t * 1024))[c];
  ushort4 a = ((const ushort4*)(y2c + (size_t)p1 * 1024))[c];
  ushort4 b = ((const ushort4*)(y2c + (size_t)p2 * 1024))[c];
  float4 o;
  o.x = bf2f(s.x) + w.x * bf2f(a.x) + w.y * bf2f(b.x);
  o.y = bf2f(s.y) + w.x * bf2f(a.y) + w.y * bf2f(b.y);
  o.z = bf2f(s.z) + w.x * bf2f(a.z) + w.y * bf2f(b.z);
  o.w = bf2f(s.w) + w.x * bf2f(a.w) + w.y * bf2f(b.w);
  ((float4*)(out + (size_t)t * 1024))[c] = o;
}

// ---------------- host ----------------
extern "C" void kernel_launch(void* const* d_in, const int* in_sizes, int n_in,
                              void* d_out, int out_size, void* d_ws, size_t ws_size,
                              hipStream_t stream) {
  const float* x = (const float*)d_in[0];
  const float* scorer_w = (const float*)d_in[1];
  const float* scorer_b = (const float*)d_in[2];
  const float* p1_w = (const float*)d_in[3];
  const float* p1_b = (const float*)d_in[4];
  const float* p2_w = (const float*)d_in[5];
  const float* p2_b = (const float*)d_in[6];
  const float* ew1_w = (const float*)d_in[7];
  const float* ew1_a = (const float*)d_in[8];
  const float* ew1_b = (const float*)d_in[9];
  const float* ew2_w = (const float*)d_in[10];
  const float* ew2_a = (const float*)d_in[11];
  const float* ew2_b = (const float*)d_in[12];
  const float* ew3_w = (const float*)d_in[13];
  const float* ew3_a = (const float*)d_in[14];
  const float* ew3_b = (const float*)d_in[15];
  const float* s1_w = (const float*)d_in[16];
  const float* s1_a = (const float*)d_in[17];
  const float* s1_b = (const float*)d_in[18];
  const float* s2_w = (const float*)d_in[19];
  const float* s2_a = (const float*)d_in[20];
  const float* s2_b = (const float*)d_in[21];
  const float* s3_w = (const float*)d_in[22];
  const float* s3_a = (const float*)d_in[23];
  const float* s3_b = (const float*)d_in[24];
  float* outf = (float*)d_out;

  char* w = (char*)d_ws;
  auto alloc = [&](size_t bytes) { char* p = w; w += (bytes + 255) & ~(size_t)255; return p; };
  u16* xfb  = (u16*)alloc((size_t)TTOK * DDIM * 2);
  u16* ph   = (u16*)alloc((size_t)TTOK * HDIM * 2);
  u16* p1wb = (u16*)alloc((size_t)HDIM * DDIM * 2);
  u16* Adst = (u16*)alloc((size_t)1179648 * 2);
  u16* Bdst = (u16*)alloc((size_t)1474560 * 2);
  u16* Wraw = (u16*)alloc((size_t)27 * 524288 * 2);
  u16* W13  = (u16*)alloc((size_t)9 * 1024 * 1024 * 2);
  u16* W2e  = (u16*)alloc((size_t)9 * 1024 * 512 * 2);
  u16* h2c  = (u16*)alloc((size_t)CROWS * FDIM * 2);
  u16* y2c  = (u16*)alloc((size_t)CROWS * DDIM * 2);
  float* base = (float*)alloc((size_t)TTOK * 8 * 4);
  float* pol  = (float*)alloc((size_t)TTOK * 8 * 4);
  float* partials = (float*)alloc(16 * 10 * 4);
  float* amaxW = (float*)alloc(27 * 4);   // 256B-aligned slot
  int* cnt    = (int*)alloc(8 * 4);       // next 256B slot (amaxW + 256B)
  int2* blkmap = (int2*)alloc(64 * 8);
  int* nbrow  = (int*)alloc(4);
  int* tokmap = (int*)alloc(CROWS * 4);
  int* posb   = (int*)alloc(TTOK * 2 * 4);
  int* idx2   = (int*)alloc(TTOK * 4);
  float2* wb  = (float2*)alloc(TTOK * 8);

  // amaxW and cnt are adjacent 256B-aligned slots: one memset covers both
  hipMemsetAsync(amaxW, 0, 256 + 8 * 4, stream);

  // 1. W amax + W->bf16 single pass (4 independent loads/thread)
  {
    AmaxCArgs a{};
    for (int e = 0; e < 8; e++) {
      a.W[e] = ew1_w + (size_t)e * 524288;
      a.W[8 + e] = ew3_w + (size_t)e * 524288;
      a.W[18 + e] = ew2_w + (size_t)e * 524288;
    }
    a.W[16] = s1_w; a.W[17] = s3_w; a.W[26] = s2_w;
    a.Wraw = Wraw; a.amax = amaxW;
    hipLaunchKernelGGL(amax_convw, dim3(128, 27), dim3(256), 0, stream, a);
  }
  // 2. conversions (load-balanced grid)
  {
    ConvArgs c{};
    c.xf = x; c.xfb = xfb; c.p1w = p1_w; c.p1wb = p1wb;
    for (int e = 0; e < 8; e++) {
      c.Asrc[e] = ew1_a + (size_t)e * 32768;
      c.Asrc[8 + e] = ew3_a + (size_t)e * 32768;
      c.Asrc[18 + e] = ew2_a + (size_t)e * 65536;
      c.Bsrc[e] = ew1_b + (size_t)e * 65536;
      c.Bsrc[8 + e] = ew3_b + (size_t)e * 65536;
      c.Bsrc[18 + e] = ew2_b + (size_t)e * 32768;
    }
    c.Asrc[16] = s1_a; c.Asrc[17] = s3_a; c.Asrc[26] = s2_a;
    c.Bsrc[16] = s1_b; c.Bsrc[17] = s3_b; c.Bsrc[26] = s2_b;
    c.Adst = Adst; c.Bdst = Bdst;
    hipLaunchKernelGGL(convert_kernel, dim3(1024, 4), dim3(256), 0, stream, c);
  }
  // 3. router hidden GEMM (128^2 tile)
  {
    Gemm128Args g{xfb, p1wb, ph, HDIM, DDIM, p1_b};
    hipLaunchKernelGGL(gemm128, dim3(32, 2), dim3(256), 0, stream, g);
  }
  // 4. merged LoRA fold (27 tensors, reads Wraw bf16, LDS-staged epilogue)
  {
    FoldArgs g{Adst, Bdst, Wraw, W13, W2e, amaxW};
    hipLaunchKernelGGL(gemm_fold, dim3(8, 8, 27), dim3(256), 0, stream, g);
  }
  // 5. router small
  {
    RouterArgs r{};
    r.xf = x; r.ph = ph; r.sw = scorer_w; r.sb = scorer_b;
    r.p2w = p2_w; r.p2b = p2_b; r.base = base; r.pol = pol;
    hipLaunchKernelGGL(router_small, dim3(256), dim3(256), 0, stream, r);
  }
  // 6. router topk + counts
  {
    FinArgs f{base, pol, partials, idx2, wb, cnt};
    hipLaunchKernelGGL(router_topk, dim3(16), dim3(256), 0, stream, f);
  }
  // 7. compaction + setup + losses (9 blocks)
  hipLaunchKernelGGL(compact_setup, dim3(9), dim3(256), 0, stream,
                     idx2, cnt, blkmap, nbrow, tokmap, posb, partials,
                     outf + (size_t)TTOK * DDIM);
  // 8. y13 + fused h2 over gathered rows
  {
    GemmGArgs g{xfb, W13, h2c, tokmap, blkmap, nbrow};
    hipLaunchKernelGGL(gemm256g<1>, dim3(56, 4), dim3(512), 0, stream, g);
  }
  // 9. y2 over concat rows
  {
    GemmGArgs g{h2c, W2e, y2c, tokmap, blkmap, nbrow};
    hipLaunchKernelGGL(gemm256g<0>, dim3(56, 4), dim3(512), 0, stream, g);
  }
  // 10. deterministic combine
  hipLaunchKernelGGL(combine_g, dim3(4096), dim3(256), 0, stream, y2c, posb, wb, outf);
}

// Round 13
// 165.576 us; speedup vs baseline: 1.3630x; 1.2209x over previous
//
#include <hip/hip_runtime.h>

#define TTOK 4096
#define DDIM 1024
#define FDIM 512
#define NEXP 8
#define HDIM 256
#define RLORA 64
#define CROWS 14336   // 4096 shared + up to 10240 padded expert rows

using u16 = unsigned short;
using f4v = __attribute__((ext_vector_type(4))) float;
using bfrag = __attribute__((ext_vector_type(8))) short;
using u16x8 = __attribute__((ext_vector_type(8))) unsigned short;

static __device__ __forceinline__ float bf2f(u16 u) {
  union { unsigned int u; float f; } x; x.u = ((unsigned int)u) << 16; return x.f;
}
static __device__ __forceinline__ u16 f2bf(float f) {
  union { float f; unsigned int u; } x; x.f = f;
  unsigned int r = (x.u + 0x7fffu + ((x.u >> 16) & 1u)) >> 16;
  return (u16)r;
}
static __device__ __forceinline__ float fq1(float t, float s) {
  float q = rintf(t / s);
  q = fminf(fmaxf(q, -128.f), 127.f);
  return q * s;
}

// ============ 256x256 BK=64 8-wave dbuf GEMM over gathered token rows ============
struct GemmGArgs {
  const u16* A; const u16* B; u16* C;
  const int* tokmap; const int2* blkmap; const int* nbrow;
};

#define STAGE1(d, kt, h, l) \
  __builtin_amdgcn_global_load_lds( \
    (const __attribute__((address_space(1))) void*)(gs[(h)*2+(l)] + (size_t)(kt)*64), \
    (__attribute__((address_space(3))) void*)&lds[(d)*32768 + (h)*8192 + (tid + (l)*512)*8], \
    16, 0, 0)

template <int MODE>
__global__ __launch_bounds__(512, 2) void gemm256g(GemmGArgs g) {
  const int br = blockIdx.x;
  if (br >= g.nbrow[0]) return;
  const int2 bm = g.blkmap[br];
  const int e = bm.x;
  const int m0 = bm.y;
  const int n0 = blockIdx.y * 256;
  const int tid = threadIdx.x;
  const int lane = tid & 63;
  const int wave = tid >> 6;
  const int wr = wave >> 2;
  const int wc = wave & 3;

  constexpr int K = MODE ? 1024 : 512;
  const u16* Bp = g.B + (size_t)e * (MODE ? 1048576 : 524288);

  __shared__ u16 lds[65536];

  // Swizzle: physical 16B-granule p of row r holds logical granule p^(r&7)
  // (pre-swizzled global source; gload_lds dest linear; readers XOR).
  const u16* gs[8];
#pragma unroll
  for (int h = 0; h < 4; h++)
#pragma unroll
    for (int l = 0; l < 2; l++) {
      const int slot = tid + l * 512;
      const int row = slot >> 3, p = slot & 7;
      const int glog = p ^ (row & 7);
      const u16* basep;
      if (h < 2) {
        const int grow = m0 + h * 128 + row;
        const int t = MODE ? g.tokmap[grow] : grow;
        basep = g.A + (size_t)t * K;
      } else {
        basep = Bp + (size_t)(n0 + (h - 2) * 128 + row) * K;
      }
      gs[h * 2 + l] = basep + glog * 8;
    }

  f4v acc[8][4];
#pragma unroll
  for (int i = 0; i < 8; i++)
#pragma unroll
    for (int j = 0; j < 4; j++) acc[i][j] = (f4v){0.f, 0.f, 0.f, 0.f};

  const int q = lane >> 4;
  const int lx = lane & 7;
  const int l15 = lane & 15;

#pragma unroll
  for (int h = 0; h < 4; h++) { STAGE1(0, 0, h, 0); STAGE1(0, 0, h, 1); }
  __syncthreads();

  constexpr int nt = K >> 6;
  for (int kt = 0; kt < nt; ++kt) {
    const int d = kt & 1;
    const int dn = d ^ 1;
    const bool more = (kt + 1 < nt);
#pragma unroll
    for (int kk = 0; kk < 2; ++kk) {
      if (more) {
        if (kk == 0) { STAGE1(dn, kt + 1, 0, 0); STAGE1(dn, kt + 1, 0, 1);
                       STAGE1(dn, kt + 1, 1, 0); STAGE1(dn, kt + 1, 1, 1); }
        else         { STAGE1(dn, kt + 1, 2, 0); STAGE1(dn, kt + 1, 2, 1);
                       STAGE1(dn, kt + 1, 3, 0); STAGE1(dn, kt + 1, 3, 1); }
      }
      bfrag afr[8], bfr[4];
      const int pa = ((kk * 4 + q) ^ lx) << 3;
      const int abase = d * 32768 + wr * 8192 + l15 * 64 + pa;
#pragma unroll
      for (int mi = 0; mi < 8; mi++) afr[mi] = *(const bfrag*)&lds[abase + mi * 1024];
      const int bbase = d * 32768 + (2 + (wc >> 1)) * 8192 + (((wc & 1) << 6) + l15) * 64 + pa;
#pragma unroll
      for (int ni = 0; ni < 4; ni++) bfr[ni] = *(const bfrag*)&lds[bbase + ni * 1024];
      __builtin_amdgcn_s_setprio(1);
#pragma unroll
      for (int mi = 0; mi < 8; mi++)
#pragma unroll
        for (int ni = 0; ni < 4; ni++)
          acc[mi][ni] = __builtin_amdgcn_mfma_f32_16x16x32_bf16(afr[mi], bfr[ni], acc[mi][ni], 0, 0, 0);
      __builtin_amdgcn_s_setprio(0);
    }
    __syncthreads();
  }

  const int crow0 = m0 + wr * 128 + q * 4;

  if (MODE == 1) {
    // fused h2 epilogue: y3 (wc>=2) -> LDS, y1-waves store h2 = y1*sigmoid(y3)
    float* xlds = (float*)lds;
    const int lrow0 = wr * 128 + q * 4;
    if (wc >= 2) {
      const int lc = (wc - 2) * 64 + l15;
#pragma unroll
      for (int mi = 0; mi < 8; mi++)
#pragma unroll
        for (int ni = 0; ni < 4; ni++)
#pragma unroll
          for (int r = 0; r < 4; r++)
            xlds[(lrow0 + mi * 16 + r) * 128 + lc + ni * 16] = acc[mi][ni][r];
    }
    __syncthreads();
    if (wc < 2) {
      const int lc = wc * 64 + l15;
      const int fbase = (n0 >> 1) + lc;
#pragma unroll
      for (int mi = 0; mi < 8; mi++)
#pragma unroll
        for (int r = 0; r < 4; r++) {
          const int rowg = crow0 + mi * 16 + r;
          const int lr = lrow0 + mi * 16 + r;
#pragma unroll
          for (int ni = 0; ni < 4; ni++) {
            float y1 = acc[mi][ni][r];
            float y3 = xlds[lr * 128 + lc + ni * 16];
            float h = y1 / (1.f + __expf(-y3));
            g.C[(size_t)rowg * FDIM + fbase + ni * 16] = f2bf(h);
          }
        }
    }
  } else {
    const int ccol0 = n0 + wc * 64 + l15;
#pragma unroll
    for (int mi = 0; mi < 8; mi++)
#pragma unroll
      for (int ni = 0; ni < 4; ni++) {
        const int col = ccol0 + ni * 16;
#pragma unroll
        for (int r = 0; r < 4; r++)
          g.C[(size_t)(crow0 + mi * 16 + r) * 1024 + col] = f2bf(acc[mi][ni][r]);
      }
  }
}

// ============ merged LoRA fold (27 tensors): C_bf16 = fq(Wraw_bf16, sW[z]) + A@B^T ============
// z<18: W13 geometry M=512,N=1024 (w1/w3 row-interleaved output); z>=18: W2 M=1024,N=512.
// sW reduced in-kernel from amaxP[z][0..127] (plain-store partials, no memset needed).
struct FoldArgs {
  const u16* A0; const u16* B0;
  const u16* Wb;           // bf16 W, tensor z at z*524288
  u16* C13; u16* C2e;
  const float* amaxP;      // [27][128]
};

__global__ __launch_bounds__(256) void gemm_fold(FoldArgs g) {
  const int z = blockIdx.z;
  const bool is13 = z < 18;
  const int bx = blockIdx.x, by = blockIdx.y;
  if (is13 ? (bx >= 4) : (by >= 4)) return;
  const int N = is13 ? 1024 : 512;
  const int K = 64;
  const u16* Ap = is13 ? g.A0 + (size_t)z * 32768 : g.A0 + 589824 + (size_t)(z - 18) * 65536;
  const u16* Bp = is13 ? g.B0 + (size_t)z * 65536 : g.B0 + 1179648 + (size_t)(z - 18) * 32768;
  const u16* Wf = g.Wb + (size_t)z * 524288;
  u16* Cb; int flag;
  if (is13) {
    const int slot = (z >= 16) ? 8 : (z & 7);
    Cb = g.C13 + (size_t)slot * 1048576;
    flag = (z >= 8 && z < 16) || z == 17 ? 2 : 1;
  } else {
    Cb = g.C2e + (size_t)(z - 18) * 524288;
    flag = 0;
  }

  const int tid = threadIdx.x;
  const int lane = tid & 63;
  const int wave = tid >> 6;
  const int wr = wave >> 1, wc = wave & 1;
  const int m0 = bx * 128, n0 = by * 128;

  __shared__ u16 As[128 * 32];
  __shared__ u16 Bs[128 * 32];
  __shared__ u16 stage[128 * 136];
  __shared__ float s_sw;

  // reduce this tensor's 128 amax partials (wave 0)
  if (wave == 0) {
    float m = fmaxf(g.amaxP[z * 128 + lane], g.amaxP[z * 128 + 64 + lane]);
#pragma unroll
    for (int off = 32; off > 0; off >>= 1) m = fmaxf(m, __shfl_xor(m, off));
    if (lane == 0) s_sw = fmaxf(m / 127.f, 1e-8f);
  }

  const int ldrow = tid >> 2;
  const int swzcol = (((tid & 3) ^ ((tid >> 3) & 3)) << 3);
  const u16* ga = Ap + (size_t)(m0 + ldrow) * K + swzcol;
  const u16* gb = Bp + (size_t)(n0 + ldrow) * K + swzcol;
  const size_t rowstep = (size_t)64 * K;

  f4v acc[4][4];
#pragma unroll
  for (int i = 0; i < 4; i++)
#pragma unroll
    for (int j = 0; j < 4; j++) acc[i][j] = (f4v){0.f, 0.f, 0.f, 0.f};

  const int rbase = lane & 15;
  const int q = lane >> 4;
  const int pg = (q ^ ((rbase >> 1) & 3)) << 3;
  const int arow = (wr << 6) + rbase;
  const int brow = (wc << 6) + rbase;

  for (int kt = 0; kt < K; kt += 32) {
    __builtin_amdgcn_global_load_lds((const __attribute__((address_space(1))) void*)(ga),
        (__attribute__((address_space(3))) void*)&As[tid * 8], 16, 0, 0);
    __builtin_amdgcn_global_load_lds((const __attribute__((address_space(1))) void*)(ga + rowstep),
        (__attribute__((address_space(3))) void*)&As[(256 + tid) * 8], 16, 0, 0);
    __builtin_amdgcn_global_load_lds((const __attribute__((address_space(1))) void*)(gb),
        (__attribute__((address_space(3))) void*)&Bs[tid * 8], 16, 0, 0);
    __builtin_amdgcn_global_load_lds((const __attribute__((address_space(1))) void*)(gb + rowstep),
        (__attribute__((address_space(3))) void*)&Bs[(256 + tid) * 8], 16, 0, 0);
    ga += 32; gb += 32;
    __syncthreads();
    bfrag af[4], bf[4];
#pragma unroll
    for (int mi = 0; mi < 4; mi++)
      af[mi] = *(const bfrag*)&As[(arow + mi * 16) * 32 + pg];
#pragma unroll
    for (int ni = 0; ni < 4; ni++)
      bf[ni] = *(const bfrag*)&Bs[(brow + ni * 16) * 32 + pg];
#pragma unroll
    for (int mi = 0; mi < 4; mi++)
#pragma unroll
      for (int ni = 0; ni < 4; ni++)
        acc[mi][ni] = __builtin_amdgcn_mfma_f32_16x16x32_bf16(af[mi], bf[ni], acc[mi][ni], 0, 0, 0);
    __syncthreads();
  }

  // acc -> LDS (bf16, padded row 136)
  const int lrow0 = (wr << 6) + ((lane >> 4) << 2);
  const int lcol0 = (wc << 6) + (lane & 15);
#pragma unroll
  for (int mi = 0; mi < 4; mi++)
#pragma unroll
    for (int ni = 0; ni < 4; ni++) {
      const int n = lcol0 + ni * 16;
#pragma unroll
      for (int r = 0; r < 4; r++)
        stage[(lrow0 + mi * 16 + r) * 136 + n] = f2bf(acc[mi][ni][r]);
    }
  __syncthreads();
  const float sw = s_sw;

  // coalesced pass: 2048 ushort8 slots (128 rows x 16 slots), W read in bf16
  const int dm0 = flag ? (((m0 >> 7) << 8) + (flag == 2 ? 128 : 0)) : m0;
#pragma unroll
  for (int j = 0; j < 8; j++) {
    const int s = j * 256 + tid;
    const int lr = s >> 4;
    const int n8 = (s & 15) << 3;
    const u16x8 wv = *(const u16x8*)&Wf[(size_t)(m0 + lr) * N + n0 + n8];
    const bfrag sv = *(const bfrag*)&stage[lr * 136 + n8];
    u16x8 o;
#pragma unroll
    for (int k = 0; k < 8; k++)
      o[k] = f2bf(fq1(bf2f(wv[k]), sw) + bf2f((u16)sv[k]));
    *(u16x8*)&Cb[(size_t)(dm0 + lr) * N + n0 + n8] = o;
  }
}

// ============ 64x64 BK=32 GEMM (router hidden): C = relu(A@B^T + bias) ============
// R9-proven: 256 blocks (occupancy matters more than fetch bytes here — R12 lesson).
struct Gemm64Args { const u16* A; const u16* B; u16* Cb; int M, N, K; const float* bias; };
__global__ __launch_bounds__(256) void gemm64(Gemm64Args g) {
  const int tid = threadIdx.x;
  const int lane = tid & 63;
  const int wave = tid >> 6;
  const int wr = wave >> 1, wc = wave & 1;
  const int m0 = blockIdx.x * 64, n0 = blockIdx.y * 64;
  const int K = g.K, N = g.N;

  __shared__ u16 As[64 * 32];
  __shared__ u16 Bs[64 * 32];

  const int ldrow = tid >> 2;
  const int swzcol = (((tid & 3) ^ ((tid >> 3) & 3)) << 3);
  const u16* ga = g.A + (size_t)(m0 + ldrow) * K + swzcol;
  const u16* gb = g.B + (size_t)(n0 + ldrow) * K + swzcol;

  f4v acc[2][2];
#pragma unroll
  for (int i = 0; i < 2; i++)
#pragma unroll
    for (int j = 0; j < 2; j++) acc[i][j] = (f4v){0.f, 0.f, 0.f, 0.f};

  const int rbase = lane & 15;
  const int q = lane >> 4;
  const int pg = (q ^ ((rbase >> 1) & 3)) << 3;
  const int arow = (wr << 5) + rbase;
  const int brow = (wc << 5) + rbase;

  for (int kt = 0; kt < K; kt += 32) {
    __builtin_amdgcn_global_load_lds((const __attribute__((address_space(1))) void*)(ga),
        (__attribute__((address_space(3))) void*)&As[tid * 8], 16, 0, 0);
    __builtin_amdgcn_global_load_lds((const __attribute__((address_space(1))) void*)(gb),
        (__attribute__((address_space(3))) void*)&Bs[tid * 8], 16, 0, 0);
    ga += 32; gb += 32;
    __syncthreads();
    bfrag af[2], bf[2];
#pragma unroll
    for (int mi = 0; mi < 2; mi++)
      af[mi] = *(const bfrag*)&As[(arow + mi * 16) * 32 + pg];
#pragma unroll
    for (int ni = 0; ni < 2; ni++)
      bf[ni] = *(const bfrag*)&Bs[(brow + ni * 16) * 32 + pg];
#pragma unroll
    for (int mi = 0; mi < 2; mi++)
#pragma unroll
      for (int ni = 0; ni < 2; ni++)
        acc[mi][ni] = __builtin_amdgcn_mfma_f32_16x16x32_bf16(af[mi], bf[ni], acc[mi][ni], 0, 0, 0);
    __syncthreads();
  }

  const int crow0 = m0 + (wr << 5) + ((lane >> 4) << 2);
  const int ccol0 = n0 + (wc << 5) + (lane & 15);
#pragma unroll
  for (int mi = 0; mi < 2; mi++)
#pragma unroll
    for (int ni = 0; ni < 2; ni++) {
      const int n = ccol0 + ni * 16;
      const float b = g.bias[n];
#pragma unroll
      for (int r = 0; r < 4; r++) {
        float v = fmaxf(acc[mi][ni][r] + b, 0.f);
        g.Cb[(size_t)(crow0 + mi * 16 + r) * N + n] = f2bf(v);
      }
    }
}

// ---------------- amax + W->bf16, per-block partial maxima (no atomics/memset) ----------------
struct AmaxCArgs { const float* W[27]; u16* Wraw; float* amaxP; };
__global__ __launch_bounds__(256) void amax_convw(AmaxCArgs a) {
  const int t = blockIdx.y;
  const float4* src = (const float4*)a.W[t];
  ushort4* dst = (ushort4*)(a.Wraw + (size_t)t * 524288);
  const int i0 = blockIdx.x * 256 + threadIdx.x;   // grid.x = 128 -> 32768 threads/tensor
  float4 v0 = src[i0];
  float4 v1 = src[i0 + 32768];
  float4 v2 = src[i0 + 65536];
  float4 v3 = src[i0 + 98304];
  ushort4 o0, o1, o2, o3;
  o0.x = f2bf(v0.x); o0.y = f2bf(v0.y); o0.z = f2bf(v0.z); o0.w = f2bf(v0.w);
  o1.x = f2bf(v1.x); o1.y = f2bf(v1.y); o1.z = f2bf(v1.z); o1.w = f2bf(v1.w);
  o2.x = f2bf(v2.x); o2.y = f2bf(v2.y); o2.z = f2bf(v2.z); o2.w = f2bf(v2.w);
  o3.x = f2bf(v3.x); o3.y = f2bf(v3.y); o3.z = f2bf(v3.z); o3.w = f2bf(v3.w);
  dst[i0] = o0; dst[i0 + 32768] = o1; dst[i0 + 65536] = o2; dst[i0 + 98304] = o3;
  float m01 = fmaxf(fmaxf(fabsf(v0.x), fabsf(v0.y)), fmaxf(fabsf(v0.z), fabsf(v0.w)));
  float m11 = fmaxf(fmaxf(fabsf(v1.x), fabsf(v1.y)), fmaxf(fabsf(v1.z), fabsf(v1.w)));
  float m21 = fmaxf(fmaxf(fabsf(v2.x), fabsf(v2.y)), fmaxf(fabsf(v2.z), fabsf(v2.w)));
  float m31 = fmaxf(fmaxf(fabsf(v3.x), fabsf(v3.y)), fmaxf(fabsf(v3.z), fabsf(v3.w)));
  float lmax = fmaxf(fmaxf(m01, m11), fmaxf(m21, m31));
#pragma unroll
  for (int off = 32; off > 0; off >>= 1) lmax = fmaxf(lmax, __shfl_xor(lmax, off));
  __shared__ float wm[4];
  if ((threadIdx.x & 63) == 0) wm[threadIdx.x >> 6] = lmax;
  __syncthreads();
  if (threadIdx.x == 0)
    a.amaxP[t * 128 + blockIdx.x] = fmaxf(fmaxf(wm[0], wm[1]), fmaxf(wm[2], wm[3]));
}

// ---------------- conversions: x->bf16, p1_w->bf16, loraA->bf16, Bm->Bm^T bf16 ----------------
struct ConvArgs {
  const float* xf; u16* xfb;
  const float* p1w; u16* p1wb;
  const float* Asrc[27]; u16* Adst;
  const float* Bsrc[27]; u16* Bdst;
};
__global__ __launch_bounds__(256) void convert_kernel(ConvArgs a) {
  const int g0 = blockIdx.x * 256 + threadIdx.x;
  const int stride = gridDim.x * 256;
  if (blockIdx.y == 0) {
    for (int i = g0; i < 1048576; i += stride) {
      float4 v = ((const float4*)a.xf)[i];
      ushort4 o; o.x = f2bf(v.x); o.y = f2bf(v.y); o.z = f2bf(v.z); o.w = f2bf(v.w);
      ((ushort4*)a.xfb)[i] = o;
    }
  } else if (blockIdx.y == 1) {
    for (int i = g0; i < 65536; i += stride) {
      float4 v = ((const float4*)a.p1w)[i];
      ushort4 o; o.x = f2bf(v.x); o.y = f2bf(v.y); o.z = f2bf(v.z); o.w = f2bf(v.w);
      ((ushort4*)a.p1wb)[i] = o;
    }
  } else if (blockIdx.y == 2) {
    for (int i = g0; i < 1179648; i += stride) {
      int t, off;
      if (i < 589824) { t = i >> 15; off = i & 32767; }
      else { int j = i - 589824; t = 18 + (j >> 16); off = j & 65535; }
      a.Adst[i] = f2bf(a.Asrc[t][off]);
    }
  } else {
    for (int i = g0; i < 1474560; i += stride) {
      int t, src;
      if (i < 1179648) { t = i >> 16; int off = i & 65535; src = (off & 63) * 1024 + (off >> 6); }
      else { int j = i - 1179648; t = 18 + (j >> 15); int off = j & 32767; src = (off & 63) * 512 + (off >> 6); }
      a.Bdst[i] = f2bf(a.Bsrc[t][src]);
    }
  }
}

// ---------------- router small: base = xf@scorer^T + b ; pol = ph@p2^T + b ----------------
struct RouterArgs {
  const float* xf; const u16* ph;
  const float* sw; const float* sb;
  const float* p2w; const float* p2b;
  float* base; float* pol;
};
__global__ __launch_bounds__(256) void router_small(RouterArgs a) {
  __shared__ float sw[8][1024];
  __shared__ float p2[8][256];
  const int tid = threadIdx.x;
  {
    const float4* s0 = (const float4*)a.sw;
    float4* d0 = (float4*)&sw[0][0];
    for (int i = tid; i < 2048; i += 256) d0[i] = s0[i];
    const float4* s1 = (const float4*)a.p2w;
    float4* d1 = (float4*)&p2[0][0];
    for (int i = tid; i < 512; i += 256) d1[i] = s1[i];
  }
  __syncthreads();
  const int tl = tid >> 4, s = tid & 15;
  const int token = blockIdx.x * 16 + tl;
  float acc[8] = {0,0,0,0,0,0,0,0}, pacc[8] = {0,0,0,0,0,0,0,0};
  const float4* xrow = (const float4*)(a.xf + (size_t)token * 1024);
  for (int i = 0; i < 16; i++) {
    const int d4 = i * 16 + s;
    float4 xv = xrow[d4];
#pragma unroll
    for (int e = 0; e < 8; e++) {
      float4 wv = ((const float4*)&sw[e][0])[d4];
      acc[e] += xv.x * wv.x + xv.y * wv.y + xv.z * wv.z + xv.w * wv.w;
    }
  }
  const u16* phrow = a.ph + (size_t)token * 256;
  for (int i = 0; i < 16; i++) {
    const int h = i * 16 + s;
    float pv = bf2f(phrow[h]);
#pragma unroll
    for (int e = 0; e < 8; e++) pacc[e] += pv * p2[e][h];
  }
#pragma unroll
  for (int off = 8; off > 0; off >>= 1)
#pragma unroll
    for (int e = 0; e < 8; e++) {
      acc[e] += __shfl_xor(acc[e], off);
      pacc[e] += __shfl_xor(pacc[e], off);
    }
  if (s == 0) {
#pragma unroll
    for (int e = 0; e < 8; e++) {
      a.base[token * 8 + e] = acc[e] + a.sb[e];
      a.pol[token * 8 + e] = pacc[e] + a.p2b[e];
    }
  }
}

// ---------------- router finalize: softmaxes, losses, top-2, per-block counts ----------------
struct FinArgs {
  const float* base; const float* pol;
  float* partials;
  int* idx2; float2* wb; int* histArr;   // histArr[16][8], plain stores
};
__global__ __launch_bounds__(256) void router_topk(FinArgs a) {
  const int tid = threadIdx.x;
  const int lane = tid & 63, wv = tid >> 6;
  const int token = blockIdx.x * 256 + tid;
  float b[8], p[8];
#pragma unroll
  for (int e = 0; e < 8; e++) { b[e] = a.base[token * 8 + e]; p[e] = a.pol[token * 8 + e]; }
  float pm = p[0];
#pragma unroll
  for (int e = 1; e < 8; e++) pm = fmaxf(pm, p[e]);
  float pe[8], psum = 0.f;
#pragma unroll
  for (int e = 0; e < 8; e++) { pe[e] = expf(p[e] - pm); psum += pe[e]; }
  const float pinv = 1.f / psum;
  float sl[8];
#pragma unroll
  for (int e = 0; e < 8; e++) sl[e] = (b[e] + pe[e] * pinv) * 0.5f;
  float sm = sl[0];
#pragma unroll
  for (int e = 1; e < 8; e++) sm = fmaxf(sm, sl[e]);
  float sc[8], ssum = 0.f;
#pragma unroll
  for (int e = 0; e < 8; e++) { sc[e] = expf(sl[e] - sm); ssum += sc[e]; }
  const float sinv = 1.f / ssum;
  float ent = 0.f;
#pragma unroll
  for (int e = 0; e < 8; e++) { float v = sc[e] * sinv; sc[e] = v; ent -= v * logf(v + 1e-6f); }
  float bm = b[0];
#pragma unroll
  for (int e = 1; e < 8; e++) bm = fmaxf(bm, b[e]);
  float zs = 0.f;
#pragma unroll
  for (int e = 0; e < 8; e++) zs += expf(b[e] - bm);
  const float lse = logf(zs) + bm;
  const float zt = lse * lse;
  float m1 = -1e30f, m2 = -1e30f; int i1 = 0, i2 = 0;
#pragma unroll
  for (int e = 0; e < 8; e++) {
    float v = sc[e];
    if (v > m1) { m2 = m1; i2 = i1; m1 = v; i1 = e; }
    else if (v > m2) { m2 = v; i2 = e; }
  }
  a.idx2[token] = i1 | (i2 << 8);
  a.wb[token] = make_float2(m1, m2);

  __shared__ int hist[8];
  if (tid < 8) hist[tid] = 0;
  __syncthreads();
  atomicAdd(&hist[i1], 1);
  atomicAdd(&hist[i2], 1);
  __syncthreads();
  if (tid < 8) a.histArr[blockIdx.x * 8 + tid] = hist[tid];

  // wave-shuffle partials reduction (10 values)
  float vals[10];
  vals[0] = ent; vals[1] = zt;
#pragma unroll
  for (int e = 0; e < 8; e++) vals[2 + e] = 0.f;
  vals[2 + i1] = m1; vals[2 + i2] = m2;
#pragma unroll
  for (int v = 0; v < 10; v++)
#pragma unroll
    for (int off = 32; off > 0; off >>= 1) vals[v] += __shfl_down(vals[v], off);
  __shared__ float wred[4][10];
  if (lane == 0)
#pragma unroll
    for (int v = 0; v < 10; v++) wred[wv][v] = vals[v];
  __syncthreads();
  if (tid < 10)
    a.partials[blockIdx.x * 10 + tid] = wred[0][tid] + wred[1][tid] + wred[2][tid] + wred[3][tid];
}

// ---------------- compaction + setup + losses in one launch (9 blocks) ----------------
__global__ __launch_bounds__(256) void compact_setup(const int* idx2, const int* histArr,
                                                     int2* blkmap, int* nbrow, int* tokmap,
                                                     int* posb, const float* partials, float* tail) {
  const int e = blockIdx.x;
  const int tid = threadIdx.x;
  int cntl[8];
#pragma unroll
  for (int i = 0; i < 8; i++) {
    int s = 0;
    for (int bblk = 0; bblk < 16; bblk++) s += histArr[bblk * 8 + i];
    cntl[i] = s;
  }
  if (e == 8) {
    if (tid == 0) {
      int o = 0, nb = 16;
      for (int i = 0; i < 16; i++) blkmap[i] = make_int2(8, i * 256);
      for (int ex = 0; ex < 8; ex++) {
        const int nbe = (cntl[ex] + 255) >> 8;
        for (int i = 0; i < nbe; i++) blkmap[nb++] = make_int2(ex, 4096 + o + i * 256);
        o += nbe << 8;
      }
      nbrow[0] = nb;
    } else if (tid == 64) {
      float ent = 0.f, z = 0.f, us[8] = {0,0,0,0,0,0,0,0};
      for (int i = 0; i < 16; i++) {
        ent += partials[i * 10 + 0];
        z += partials[i * 10 + 1];
        for (int ex = 0; ex < 8; ex++) us[ex] += partials[i * 10 + 2 + ex];
      }
      float tot = 0.f;
      for (int ex = 0; ex < 8; ex++) tot += us[ex];
      const float meanu = tot / 8.f;
      float uf[8], mu = 0.f;
      for (int ex = 0; ex < 8; ex++) { uf[ex] = us[ex] / (meanu + 1e-6f); mu += uf[ex]; }
      mu /= 8.f;
      float var = 0.f;
      for (int ex = 0; ex < 8; ex++) { float d = uf[ex] - mu; var += d * d; }
      var /= 7.f;
      const float bl = 0.3f * var - 0.1f * (ent / 4096.f) + 1e-4f * (z / 4096.f);
      for (int ex = 0; ex < 8; ex++) tail[ex] = us[ex];
      tail[8] = bl; tail[9] = 0.f; tail[10] = 0.f;
    }
    for (int t = tid; t < 4096; t += 256) tokmap[t] = t;
    return;
  }
  const int lane = tid & 63, wv = tid >> 6;
  __shared__ int wtot[4];
  __shared__ int carry;
  if (tid == 0) carry = 0;
  __syncthreads();
  int off = 0;
  for (int i = 0; i < e; i++) off += ((cntl[i] + 255) >> 8) << 8;
  const int base = 4096 + off;
  for (int c = 0; c < 16; c++) {
    const int t = c * 256 + tid;
    const int ii = idx2[t];
    const int i1 = ii & 255, i2 = ii >> 8;
    const int flag = (i1 == e || i2 == e) ? 1 : 0;
    const unsigned long long m = __ballot(flag);
    const int pre = __popcll(m & ((1ull << lane) - 1ull));
    if (lane == 63) wtot[wv] = pre + flag;
    __syncthreads();
    int wbase = 0;
    for (int i = 0; i < wv; i++) wbase += wtot[i];
    if (flag) {
      const int row = base + carry + wbase + pre;
      tokmap[row] = t;
      posb[t * 2 + (i2 == e ? 1 : 0)] = row;
    }
    __syncthreads();
    if (tid == 0) carry += wtot[0] + wtot[1] + wtot[2] + wtot[3];
    __syncthreads();
  }
  const int ce = cntl[e];
  const int pend = ((ce + 255) >> 8) << 8;
  for (int r = ce + tid; r < pend; r += 256) tokmap[base + r] = 0;
}

// ---------------- combine: out[t] = y2c[t] + w1*y2c[p1] + w2*y2c[p2] ----------------
__global__ __launch_bounds__(256) void combine_g(const u16* y2c, const int* posb,
                                                 const float2* wb, float* out) {
  const int t = blockIdx.x;
  const int c = threadIdx.x;
  const float2 w = wb[t];
  const int p1 = posb[t * 2], p2 = posb[t * 2 + 1];
  ushort4 s = ((const ushort4*)(y2c + (size_t)t * 1024))[c];
  ushort4 a = ((const ushort4*)(y2c + (size_t)p1 * 1024))[c];
  ushort4 b = ((const ushort4*)(y2c + (size_t)p2 * 1024))[c];
  float4 o;
  o.x = bf2f(s.x) + w.x * bf2f(a.x) + w.y * bf2f(b.x);
  o.y = bf2f(s.y) + w.x * bf2f(a.y) + w.y * bf2f(b.y);
  o.z = bf2f(s.z) + w.x * bf2f(a.z) + w.y * bf2f(b.z);
  o.w = bf2f(s.w) + w.x * bf2f(a.w) + w.y * bf2f(b.w);
  ((float4*)(out + (size_t)t * 1024))[c] = o;
}

// ---------------- host ----------------
extern "C" void kernel_launch(void* const* d_in, const int* in_sizes, int n_in,
                              void* d_out, int out_size, void* d_ws, size_t ws_size,
                              hipStream_t stream) {
  const float* x = (const float*)d_in[0];
  const float* scorer_w = (const float*)d_in[1];
  const float* scorer_b = (const float*)d_in[2];
  const float* p1_w = (const float*)d_in[3];
  const float* p1_b = (const float*)d_in[4];
  const float* p2_w = (const float*)d_in[5];
  const float* p2_b = (const float*)d_in[6];
  const float* ew1_w = (const float*)d_in[7];
  const float* ew1_a = (const float*)d_in[8];
  const float* ew1_b = (const float*)d_in[9];
  const float* ew2_w = (const float*)d_in[10];
  const float* ew2_a = (const float*)d_in[11];
  const float* ew2_b = (const float*)d_in[12];
  const float* ew3_w = (const float*)d_in[13];
  const float* ew3_a = (const float*)d_in[14];
  const float* ew3_b = (const float*)d_in[15];
  const float* s1_w = (const float*)d_in[16];
  const float* s1_a = (const float*)d_in[17];
  const float* s1_b = (const float*)d_in[18];
  const float* s2_w = (const float*)d_in[19];
  const float* s2_a = (const float*)d_in[20];
  const float* s2_b = (const float*)d_in[21];
  const float* s3_w = (const float*)d_in[22];
  const float* s3_a = (const float*)d_in[23];
  const float* s3_b = (const float*)d_in[24];
  float* outf = (float*)d_out;

  char* w = (char*)d_ws;
  auto alloc = [&](size_t bytes) { char* p = w; w += (bytes + 255) & ~(size_t)255; return p; };
  u16* xfb  = (u16*)alloc((size_t)TTOK * DDIM * 2);
  u16* ph   = (u16*)alloc((size_t)TTOK * HDIM * 2);
  u16* p1wb = (u16*)alloc((size_t)HDIM * DDIM * 2);
  u16* Adst = (u16*)alloc((size_t)1179648 * 2);
  u16* Bdst = (u16*)alloc((size_t)1474560 * 2);
  u16* Wraw = (u16*)alloc((size_t)27 * 524288 * 2);
  u16* W13  = (u16*)alloc((size_t)9 * 1024 * 1024 * 2);
  u16* W2e  = (u16*)alloc((size_t)9 * 1024 * 512 * 2);
  u16* h2c  = (u16*)alloc((size_t)CROWS * FDIM * 2);
  u16* y2c  = (u16*)alloc((size_t)CROWS * DDIM * 2);
  float* base = (float*)alloc((size_t)TTOK * 8 * 4);
  float* pol  = (float*)alloc((size_t)TTOK * 8 * 4);
  float* partials = (float*)alloc(16 * 10 * 4);
  float* amaxP = (float*)alloc(27 * 128 * 4);
  int* histArr = (int*)alloc(16 * 8 * 4);
  int2* blkmap = (int2*)alloc(64 * 8);
  int* nbrow  = (int*)alloc(4);
  int* tokmap = (int*)alloc(CROWS * 4);
  int* posb   = (int*)alloc(TTOK * 2 * 4);
  int* idx2   = (int*)alloc(TTOK * 4);
  float2* wb  = (float2*)alloc(TTOK * 8);

  // 1. W amax partials + W->bf16 single pass (no atomics -> no memset needed)
  {
    AmaxCArgs a{};
    for (int e = 0; e < 8; e++) {
      a.W[e] = ew1_w + (size_t)e * 524288;
      a.W[8 + e] = ew3_w + (size_t)e * 524288;
      a.W[18 + e] = ew2_w + (size_t)e * 524288;
    }
    a.W[16] = s1_w; a.W[17] = s3_w; a.W[26] = s2_w;
    a.Wraw = Wraw; a.amaxP = amaxP;
    hipLaunchKernelGGL(amax_convw, dim3(128, 27), dim3(256), 0, stream, a);
  }
  // 2. conversions (load-balanced grid)
  {
    ConvArgs c{};
    c.xf = x; c.xfb = xfb; c.p1w = p1_w; c.p1wb = p1wb;
    for (int e = 0; e < 8; e++) {
      c.Asrc[e] = ew1_a + (size_t)e * 32768;
      c.Asrc[8 + e] = ew3_a + (size_t)e * 32768;
      c.Asrc[18 + e] = ew2_a + (size_t)e * 65536;
      c.Bsrc[e] = ew1_b + (size_t)e * 65536;
      c.Bsrc[8 + e] = ew3_b + (size_t)e * 65536;
      c.Bsrc[18 + e] = ew2_b + (size_t)e * 32768;
    }
    c.Asrc[16] = s1_a; c.Asrc[17] = s3_a; c.Asrc[26] = s2_a;
    c.Bsrc[16] = s1_b; c.Bsrc[17] = s3_b; c.Bsrc[26] = s2_b;
    c.Adst = Adst; c.Bdst = Bdst;
    hipLaunchKernelGGL(convert_kernel, dim3(1024, 4), dim3(256), 0, stream, c);
  }
  // 3. router hidden GEMM (64^2 tile, 256 blocks — R9-proven)
  {
    Gemm64Args g{xfb, p1wb, ph, TTOK, HDIM, DDIM, p1_b};
    hipLaunchKernelGGL(gemm64, dim3(64, 4), dim3(256), 0, stream, g);
  }
  // 4. merged LoRA fold (27 tensors, reads Wraw bf16, in-kernel amax reduce)
  {
    FoldArgs g{Adst, Bdst, Wraw, W13, W2e, amaxP};
    hipLaunchKernelGGL(gemm_fold, dim3(8, 8, 27), dim3(256), 0, stream, g);
  }
  // 5. router small
  {
    RouterArgs r{};
    r.xf = x; r.ph = ph; r.sw = scorer_w; r.sb = scorer_b;
    r.p2w = p2_w; r.p2b = p2_b; r.base = base; r.pol = pol;
    hipLaunchKernelGGL(router_small, dim3(256), dim3(256), 0, stream, r);
  }
  // 6. router topk + per-block counts
  {
    FinArgs f{base, pol, partials, idx2, wb, histArr};
    hipLaunchKernelGGL(router_topk, dim3(16), dim3(256), 0, stream, f);
  }
  // 7. compaction + setup + losses (9 blocks)
  hipLaunchKernelGGL(compact_setup, dim3(9), dim3(256), 0, stream,
                     idx2, histArr, blkmap, nbrow, tokmap, posb, partials,
                     outf + (size_t)TTOK * DDIM);
  // 8. y13 + fused h2 over gathered rows
  {
    GemmGArgs g{xfb, W13, h2c, tokmap, blkmap, nbrow};
    hipLaunchKernelGGL(gemm256g<1>, dim3(56, 4), dim3(512), 0, stream, g);
  }
  // 9. y2 over concat rows
  {
    GemmGArgs g{h2c, W2e, y2c, tokmap, blkmap, nbrow};
    hipLaunchKernelGGL(gemm256g<0>, dim3(56, 4), dim3(512), 0, stream, g);
  }
  // 10. deterministic combine
  hipLaunchKernelGGL(combine_g, dim3(4096), dim3(256), 0, stream, y2c, posb, wb, outf);
}

// Round 14
// 153.344 us; speedup vs baseline: 1.4718x; 1.0798x over previous
//
#include <hip/hip_runtime.h>

#define TTOK 4096
#define DDIM 1024
#define FDIM 512
#define NEXP 8
#define HDIM 256
#define RLORA 64
#define CROWS 14336   // 4096 shared + up to 10240 padded expert rows

using u16 = unsigned short;
using f4v = __attribute__((ext_vector_type(4))) float;
using bfrag = __attribute__((ext_vector_type(8))) short;
using u16x8 = __attribute__((ext_vector_type(8))) unsigned short;

static __device__ __forceinline__ float bf2f(u16 u) {
  union { unsigned int u; float f; } x; x.u = ((unsigned int)u) << 16; return x.f;
}
static __device__ __forceinline__ u16 f2bf(float f) {
  union { float f; unsigned int u; } x; x.f = f;
  unsigned int r = (x.u + 0x7fffu + ((x.u >> 16) & 1u)) >> 16;
  return (u16)r;
}
static __device__ __forceinline__ float fq1(float t, float s) {
  float q = rintf(t / s);
  q = fminf(fmaxf(q, -128.f), 127.f);
  return q * s;
}

// ============ 256x256 BK=64 8-wave dbuf GEMM over gathered token rows ============
struct GemmGArgs {
  const u16* A; const u16* B; u16* C;
  const int* tokmap; const int2* blkmap; const int* nbrow;
};

#define STAGE1(d, kt, h, l) \
  __builtin_amdgcn_global_load_lds( \
    (const __attribute__((address_space(1))) void*)(gs[(h)*2+(l)] + (size_t)(kt)*64), \
    (__attribute__((address_space(3))) void*)&lds[(d)*32768 + (h)*8192 + (tid + (l)*512)*8], \
    16, 0, 0)

template <int MODE>
__global__ __launch_bounds__(512, 2) void gemm256g(GemmGArgs g) {
  const int br = blockIdx.x;
  if (br >= g.nbrow[0]) return;
  const int2 bm = g.blkmap[br];
  const int e = bm.x;
  const int m0 = bm.y;
  const int n0 = blockIdx.y * 256;
  const int tid = threadIdx.x;
  const int lane = tid & 63;
  const int wave = tid >> 6;
  const int wr = wave >> 2;
  const int wc = wave & 3;

  constexpr int K = MODE ? 1024 : 512;
  const u16* Bp = g.B + (size_t)e * (MODE ? 1048576 : 524288);

  __shared__ u16 lds[65536];

  // Swizzle: physical 16B-granule p of row r holds logical granule p^(r&7)
  // (pre-swizzled global source; gload_lds dest linear; readers XOR).
  const u16* gs[8];
#pragma unroll
  for (int h = 0; h < 4; h++)
#pragma unroll
    for (int l = 0; l < 2; l++) {
      const int slot = tid + l * 512;
      const int row = slot >> 3, p = slot & 7;
      const int glog = p ^ (row & 7);
      const u16* basep;
      if (h < 2) {
        const int grow = m0 + h * 128 + row;
        const int t = MODE ? g.tokmap[grow] : grow;
        basep = g.A + (size_t)t * K;
      } else {
        basep = Bp + (size_t)(n0 + (h - 2) * 128 + row) * K;
      }
      gs[h * 2 + l] = basep + glog * 8;
    }

  f4v acc[8][4];
#pragma unroll
  for (int i = 0; i < 8; i++)
#pragma unroll
    for (int j = 0; j < 4; j++) acc[i][j] = (f4v){0.f, 0.f, 0.f, 0.f};

  const int q = lane >> 4;
  const int lx = lane & 7;
  const int l15 = lane & 15;

#pragma unroll
  for (int h = 0; h < 4; h++) { STAGE1(0, 0, h, 0); STAGE1(0, 0, h, 1); }
  __syncthreads();

  constexpr int nt = K >> 6;
  for (int kt = 0; kt < nt; ++kt) {
    const int d = kt & 1;
    const int dn = d ^ 1;
    const bool more = (kt + 1 < nt);
#pragma unroll
    for (int kk = 0; kk < 2; ++kk) {
      if (more) {
        if (kk == 0) { STAGE1(dn, kt + 1, 0, 0); STAGE1(dn, kt + 1, 0, 1);
                       STAGE1(dn, kt + 1, 1, 0); STAGE1(dn, kt + 1, 1, 1); }
        else         { STAGE1(dn, kt + 1, 2, 0); STAGE1(dn, kt + 1, 2, 1);
                       STAGE1(dn, kt + 1, 3, 0); STAGE1(dn, kt + 1, 3, 1); }
      }
      bfrag afr[8], bfr[4];
      const int pa = ((kk * 4 + q) ^ lx) << 3;
      const int abase = d * 32768 + wr * 8192 + l15 * 64 + pa;
#pragma unroll
      for (int mi = 0; mi < 8; mi++) afr[mi] = *(const bfrag*)&lds[abase + mi * 1024];
      const int bbase = d * 32768 + (2 + (wc >> 1)) * 8192 + (((wc & 1) << 6) + l15) * 64 + pa;
#pragma unroll
      for (int ni = 0; ni < 4; ni++) bfr[ni] = *(const bfrag*)&lds[bbase + ni * 1024];
      __builtin_amdgcn_s_setprio(1);
#pragma unroll
      for (int mi = 0; mi < 8; mi++)
#pragma unroll
        for (int ni = 0; ni < 4; ni++)
          acc[mi][ni] = __builtin_amdgcn_mfma_f32_16x16x32_bf16(afr[mi], bfr[ni], acc[mi][ni], 0, 0, 0);
      __builtin_amdgcn_s_setprio(0);
    }
    __syncthreads();
  }

  const int crow0 = m0 + wr * 128 + q * 4;

  if (MODE == 1) {
    // fused h2 epilogue: y3 (wc>=2) -> LDS, y1-waves store h2 = y1*sigmoid(y3)
    float* xlds = (float*)lds;
    const int lrow0 = wr * 128 + q * 4;
    if (wc >= 2) {
      const int lc = (wc - 2) * 64 + l15;
#pragma unroll
      for (int mi = 0; mi < 8; mi++)
#pragma unroll
        for (int ni = 0; ni < 4; ni++)
#pragma unroll
          for (int r = 0; r < 4; r++)
            xlds[(lrow0 + mi * 16 + r) * 128 + lc + ni * 16] = acc[mi][ni][r];
    }
    __syncthreads();
    if (wc < 2) {
      const int lc = wc * 64 + l15;
      const int fbase = (n0 >> 1) + lc;
#pragma unroll
      for (int mi = 0; mi < 8; mi++)
#pragma unroll
        for (int r = 0; r < 4; r++) {
          const int rowg = crow0 + mi * 16 + r;
          const int lr = lrow0 + mi * 16 + r;
#pragma unroll
          for (int ni = 0; ni < 4; ni++) {
            float y1 = acc[mi][ni][r];
            float y3 = xlds[lr * 128 + lc + ni * 16];
            float h = y1 / (1.f + __expf(-y3));
            g.C[(size_t)rowg * FDIM + fbase + ni * 16] = f2bf(h);
          }
        }
    }
  } else {
    const int ccol0 = n0 + wc * 64 + l15;
#pragma unroll
    for (int mi = 0; mi < 8; mi++)
#pragma unroll
      for (int ni = 0; ni < 4; ni++) {
        const int col = ccol0 + ni * 16;
#pragma unroll
        for (int r = 0; r < 4; r++)
          g.C[(size_t)(crow0 + mi * 16 + r) * 1024 + col] = f2bf(acc[mi][ni][r]);
      }
  }
}

// ============ mid kernel: gemm64 (router hidden) + merged LoRA fold, one launch ============
// blocks [0,256): 64x64 tiles of ph = relu(xfb @ p1wb^T + p1_b)
// blocks [256,1984): fold tile (z = (bid-256)/64, rem%8=bx, rem/8=by) with guards.
struct MidArgs {
  // gemm64
  const u16* A64; const u16* B64; u16* C64; const float* bias64;
  // fold
  const u16* A0; const u16* B0;
  const u16* Wb;
  u16* C13; u16* C2e;
  const float* amaxP;      // [27][128]
};

__global__ __launch_bounds__(256) void mid_kernel(MidArgs g) {
  __shared__ u16 smem[25600];
  __shared__ float s_sw;
  const int bid = blockIdx.x;
  const int tid = threadIdx.x;
  const int lane = tid & 63;
  const int wave = tid >> 6;

  if (bid < 256) {
    // ---------------- gemm64: C = relu(A@B^T + bias), 64x64 tile ----------------
    const int wr = wave >> 1, wc = wave & 1;
    const int m0 = (bid & 63) * 64, n0 = (bid >> 6) * 64;
    const int K = DDIM, N = HDIM;
    u16* As = smem;            // 2048
    u16* Bs = smem + 2048;     // 2048

    const int ldrow = tid >> 2;
    const int swzcol = (((tid & 3) ^ ((tid >> 3) & 3)) << 3);
    const u16* ga = g.A64 + (size_t)(m0 + ldrow) * K + swzcol;
    const u16* gb = g.B64 + (size_t)(n0 + ldrow) * K + swzcol;

    f4v acc[2][2];
#pragma unroll
    for (int i = 0; i < 2; i++)
#pragma unroll
      for (int j = 0; j < 2; j++) acc[i][j] = (f4v){0.f, 0.f, 0.f, 0.f};

    const int rbase = lane & 15;
    const int q = lane >> 4;
    const int pg = (q ^ ((rbase >> 1) & 3)) << 3;
    const int arow = (wr << 5) + rbase;
    const int brow = (wc << 5) + rbase;

    for (int kt = 0; kt < K; kt += 32) {
      __builtin_amdgcn_global_load_lds((const __attribute__((address_space(1))) void*)(ga),
          (__attribute__((address_space(3))) void*)&As[tid * 8], 16, 0, 0);
      __builtin_amdgcn_global_load_lds((const __attribute__((address_space(1))) void*)(gb),
          (__attribute__((address_space(3))) void*)&Bs[tid * 8], 16, 0, 0);
      ga += 32; gb += 32;
      __syncthreads();
      bfrag af[2], bf[2];
#pragma unroll
      for (int mi = 0; mi < 2; mi++)
        af[mi] = *(const bfrag*)&As[(arow + mi * 16) * 32 + pg];
#pragma unroll
      for (int ni = 0; ni < 2; ni++)
        bf[ni] = *(const bfrag*)&Bs[(brow + ni * 16) * 32 + pg];
#pragma unroll
      for (int mi = 0; mi < 2; mi++)
#pragma unroll
        for (int ni = 0; ni < 2; ni++)
          acc[mi][ni] = __builtin_amdgcn_mfma_f32_16x16x32_bf16(af[mi], bf[ni], acc[mi][ni], 0, 0, 0);
      __syncthreads();
    }

    const int crow0 = m0 + (wr << 5) + ((lane >> 4) << 2);
    const int ccol0 = n0 + (wc << 5) + (lane & 15);
#pragma unroll
    for (int mi = 0; mi < 2; mi++)
#pragma unroll
      for (int ni = 0; ni < 2; ni++) {
        const int n = ccol0 + ni * 16;
        const float b = g.bias64[n];
#pragma unroll
        for (int r = 0; r < 4; r++) {
          float v = fmaxf(acc[mi][ni][r] + b, 0.f);
          g.C64[(size_t)(crow0 + mi * 16 + r) * N + n] = f2bf(v);
        }
      }
    return;
  }

  // ---------------- fold: C_bf16 = fq(Wraw, sW[z]) + A@B^T ----------------
  const int fid = bid - 256;
  const int z = fid >> 6;
  const int rem = fid & 63;
  const int bx = rem & 7, by = rem >> 3;
  const bool is13 = z < 18;
  if (is13 ? (bx >= 4) : (by >= 4)) return;
  const int N = is13 ? 1024 : 512;
  const int K = 64;
  const u16* Ap = is13 ? g.A0 + (size_t)z * 32768 : g.A0 + 589824 + (size_t)(z - 18) * 65536;
  const u16* Bp = is13 ? g.B0 + (size_t)z * 65536 : g.B0 + 1179648 + (size_t)(z - 18) * 32768;
  const u16* Wf = g.Wb + (size_t)z * 524288;
  u16* Cb; int flag;
  if (is13) {
    const int slot = (z >= 16) ? 8 : (z & 7);
    Cb = g.C13 + (size_t)slot * 1048576;
    flag = (z >= 8 && z < 16) || z == 17 ? 2 : 1;
  } else {
    Cb = g.C2e + (size_t)(z - 18) * 524288;
    flag = 0;
  }

  const int wr = wave >> 1, wc = wave & 1;
  const int m0 = bx * 128, n0 = by * 128;
  u16* As = smem;             // 4096
  u16* Bs = smem + 4096;      // 4096
  u16* stage = smem + 8192;   // 17408

  // reduce this tensor's 128 amax partials (wave 0)
  if (wave == 0) {
    float m = fmaxf(g.amaxP[z * 128 + lane], g.amaxP[z * 128 + 64 + lane]);
#pragma unroll
    for (int off = 32; off > 0; off >>= 1) m = fmaxf(m, __shfl_xor(m, off));
    if (lane == 0) s_sw = fmaxf(m / 127.f, 1e-8f);
  }

  const int ldrow = tid >> 2;
  const int swzcol = (((tid & 3) ^ ((tid >> 3) & 3)) << 3);
  const u16* ga = Ap + (size_t)(m0 + ldrow) * K + swzcol;
  const u16* gb = Bp + (size_t)(n0 + ldrow) * K + swzcol;
  const size_t rowstep = (size_t)64 * K;

  f4v acc[4][4];
#pragma unroll
  for (int i = 0; i < 4; i++)
#pragma unroll
    for (int j = 0; j < 4; j++) acc[i][j] = (f4v){0.f, 0.f, 0.f, 0.f};

  const int rbase = lane & 15;
  const int q = lane >> 4;
  const int pg = (q ^ ((rbase >> 1) & 3)) << 3;
  const int arow = (wr << 6) + rbase;
  const int brow = (wc << 6) + rbase;

  for (int kt = 0; kt < K; kt += 32) {
    __builtin_amdgcn_global_load_lds((const __attribute__((address_space(1))) void*)(ga),
        (__attribute__((address_space(3))) void*)&As[tid * 8], 16, 0, 0);
    __builtin_amdgcn_global_load_lds((const __attribute__((address_space(1))) void*)(ga + rowstep),
        (__attribute__((address_space(3))) void*)&As[(256 + tid) * 8], 16, 0, 0);
    __builtin_amdgcn_global_load_lds((const __attribute__((address_space(1))) void*)(gb),
        (__attribute__((address_space(3))) void*)&Bs[tid * 8], 16, 0, 0);
    __builtin_amdgcn_global_load_lds((const __attribute__((address_space(1))) void*)(gb + rowstep),
        (__attribute__((address_space(3))) void*)&Bs[(256 + tid) * 8], 16, 0, 0);
    ga += 32; gb += 32;
    __syncthreads();
    bfrag af[4], bf[4];
#pragma unroll
    for (int mi = 0; mi < 4; mi++)
      af[mi] = *(const bfrag*)&As[(arow + mi * 16) * 32 + pg];
#pragma unroll
    for (int ni = 0; ni < 4; ni++)
      bf[ni] = *(const bfrag*)&Bs[(brow + ni * 16) * 32 + pg];
#pragma unroll
    for (int mi = 0; mi < 4; mi++)
#pragma unroll
      for (int ni = 0; ni < 4; ni++)
        acc[mi][ni] = __builtin_amdgcn_mfma_f32_16x16x32_bf16(af[mi], bf[ni], acc[mi][ni], 0, 0, 0);
    __syncthreads();
  }

  // acc -> LDS (bf16, padded row 136)
  const int lrow0 = (wr << 6) + ((lane >> 4) << 2);
  const int lcol0 = (wc << 6) + (lane & 15);
#pragma unroll
  for (int mi = 0; mi < 4; mi++)
#pragma unroll
    for (int ni = 0; ni < 4; ni++) {
      const int n = lcol0 + ni * 16;
#pragma unroll
      for (int r = 0; r < 4; r++)
        stage[(lrow0 + mi * 16 + r) * 136 + n] = f2bf(acc[mi][ni][r]);
    }
  __syncthreads();
  const float sw = s_sw;

  // coalesced pass: 2048 ushort8 slots (128 rows x 16 slots), W read in bf16
  const int dm0 = flag ? (((m0 >> 7) << 8) + (flag == 2 ? 128 : 0)) : m0;
#pragma unroll
  for (int j = 0; j < 8; j++) {
    const int s = j * 256 + tid;
    const int lr = s >> 4;
    const int n8 = (s & 15) << 3;
    const u16x8 wv = *(const u16x8*)&Wf[(size_t)(m0 + lr) * N + n0 + n8];
    const bfrag sv = *(const bfrag*)&stage[lr * 136 + n8];
    u16x8 o;
#pragma unroll
    for (int k = 0; k < 8; k++)
      o[k] = f2bf(fq1(bf2f(wv[k]), sw) + bf2f((u16)sv[k]));
    *(u16x8*)&Cb[(size_t)(dm0 + lr) * N + n0 + n8] = o;
  }
}

// ---------------- prep: amax+convW (blocks 0..3455) + conversions (3456..7551) ----------------
struct PrepArgs {
  const float* W[27]; u16* Wraw; float* amaxP;
  const float* xf; u16* xfb;
  const float* p1w; u16* p1wb;
  const float* Asrc[27]; u16* Adst;
  const float* Bsrc[27]; u16* Bdst;
};
__global__ __launch_bounds__(256) void prep_kernel(PrepArgs a) {
  const int bid = blockIdx.x;
  const int tid = threadIdx.x;
  if (bid < 3456) {
    // amax partials + W->bf16 (R11/R13-proven: 4 independent float4/thread)
    const int t = bid >> 7;
    const int bx = bid & 127;
    const float4* src = (const float4*)a.W[t];
    ushort4* dst = (ushort4*)(a.Wraw + (size_t)t * 524288);
    const int i0 = bx * 256 + tid;
    float4 v0 = src[i0];
    float4 v1 = src[i0 + 32768];
    float4 v2 = src[i0 + 65536];
    float4 v3 = src[i0 + 98304];
    ushort4 o0, o1, o2, o3;
    o0.x = f2bf(v0.x); o0.y = f2bf(v0.y); o0.z = f2bf(v0.z); o0.w = f2bf(v0.w);
    o1.x = f2bf(v1.x); o1.y = f2bf(v1.y); o1.z = f2bf(v1.z); o1.w = f2bf(v1.w);
    o2.x = f2bf(v2.x); o2.y = f2bf(v2.y); o2.z = f2bf(v2.z); o2.w = f2bf(v2.w);
    o3.x = f2bf(v3.x); o3.y = f2bf(v3.y); o3.z = f2bf(v3.z); o3.w = f2bf(v3.w);
    dst[i0] = o0; dst[i0 + 32768] = o1; dst[i0 + 65536] = o2; dst[i0 + 98304] = o3;
    float m01 = fmaxf(fmaxf(fabsf(v0.x), fabsf(v0.y)), fmaxf(fabsf(v0.z), fabsf(v0.w)));
    float m11 = fmaxf(fmaxf(fabsf(v1.x), fabsf(v1.y)), fmaxf(fabsf(v1.z), fabsf(v1.w)));
    float m21 = fmaxf(fmaxf(fabsf(v2.x), fabsf(v2.y)), fmaxf(fabsf(v2.z), fabsf(v2.w)));
    float m31 = fmaxf(fmaxf(fabsf(v3.x), fabsf(v3.y)), fmaxf(fabsf(v3.z), fabsf(v3.w)));
    float lmax = fmaxf(fmaxf(m01, m11), fmaxf(m21, m31));
#pragma unroll
    for (int off = 32; off > 0; off >>= 1) lmax = fmaxf(lmax, __shfl_xor(lmax, off));
    __shared__ float wm[4];
    if ((tid & 63) == 0) wm[tid >> 6] = lmax;
    __syncthreads();
    if (tid == 0)
      a.amaxP[t * 128 + bx] = fmaxf(fmaxf(wm[0], wm[1]), fmaxf(wm[2], wm[3]));
    return;
  }
  // conversions (R7-proven grid: 1024 x-blocks per slice, 4 slices)
  const int cid = bid - 3456;
  const int slice = cid >> 10;
  const int g0 = (cid & 1023) * 256 + tid;
  const int stride = 262144;
  if (slice == 0) {
    for (int i = g0; i < 1048576; i += stride) {
      float4 v = ((const float4*)a.xf)[i];
      ushort4 o; o.x = f2bf(v.x); o.y = f2bf(v.y); o.z = f2bf(v.z); o.w = f2bf(v.w);
      ((ushort4*)a.xfb)[i] = o;
    }
  } else if (slice == 1) {
    for (int i = g0; i < 65536; i += stride) {
      float4 v = ((const float4*)a.p1w)[i];
      ushort4 o; o.x = f2bf(v.x); o.y = f2bf(v.y); o.z = f2bf(v.z); o.w = f2bf(v.w);
      ((ushort4*)a.p1wb)[i] = o;
    }
  } else if (slice == 2) {
    for (int i = g0; i < 1179648; i += stride) {
      int t, off;
      if (i < 589824) { t = i >> 15; off = i & 32767; }
      else { int j = i - 589824; t = 18 + (j >> 16); off = j & 65535; }
      a.Adst[i] = f2bf(a.Asrc[t][off]);
    }
  } else {
    for (int i = g0; i < 1474560; i += stride) {
      int t, src;
      if (i < 1179648) { t = i >> 16; int off = i & 65535; src = (off & 63) * 1024 + (off >> 6); }
      else { int j = i - 1179648; t = 18 + (j >> 15); int off = j & 32767; src = (off & 63) * 512 + (off >> 6); }
      a.Bdst[i] = f2bf(a.Bsrc[t][src]);
    }
  }
}

// ---------------- router small: base = xf@scorer^T + b ; pol = ph@p2^T + b ----------------
struct RouterArgs {
  const float* xf; const u16* ph;
  const float* sw; const float* sb;
  const float* p2w; const float* p2b;
  float* base; float* pol;
};
__global__ __launch_bounds__(256) void router_small(RouterArgs a) {
  __shared__ float sw[8][1024];
  __shared__ float p2[8][256];
  const int tid = threadIdx.x;
  {
    const float4* s0 = (const float4*)a.sw;
    float4* d0 = (float4*)&sw[0][0];
    for (int i = tid; i < 2048; i += 256) d0[i] = s0[i];
    const float4* s1 = (const float4*)a.p2w;
    float4* d1 = (float4*)&p2[0][0];
    for (int i = tid; i < 512; i += 256) d1[i] = s1[i];
  }
  __syncthreads();
  const int tl = tid >> 4, s = tid & 15;
  const int token = blockIdx.x * 16 + tl;
  float acc[8] = {0,0,0,0,0,0,0,0}, pacc[8] = {0,0,0,0,0,0,0,0};
  const float4* xrow = (const float4*)(a.xf + (size_t)token * 1024);
  for (int i = 0; i < 16; i++) {
    const int d4 = i * 16 + s;
    float4 xv = xrow[d4];
#pragma unroll
    for (int e = 0; e < 8; e++) {
      float4 wv = ((const float4*)&sw[e][0])[d4];
      acc[e] += xv.x * wv.x + xv.y * wv.y + xv.z * wv.z + xv.w * wv.w;
    }
  }
  const u16* phrow = a.ph + (size_t)token * 256;
  for (int i = 0; i < 16; i++) {
    const int h = i * 16 + s;
    float pv = bf2f(phrow[h]);
#pragma unroll
    for (int e = 0; e < 8; e++) pacc[e] += pv * p2[e][h];
  }
#pragma unroll
  for (int off = 8; off > 0; off >>= 1)
#pragma unroll
    for (int e = 0; e < 8; e++) {
      acc[e] += __shfl_xor(acc[e], off);
      pacc[e] += __shfl_xor(pacc[e], off);
    }
  if (s == 0) {
#pragma unroll
    for (int e = 0; e < 8; e++) {
      a.base[token * 8 + e] = acc[e] + a.sb[e];
      a.pol[token * 8 + e] = pacc[e] + a.p2b[e];
    }
  }
}

// ---------------- router finalize: softmaxes, losses, top-2, per-block counts ----------------
struct FinArgs {
  const float* base; const float* pol;
  float* partials;
  int* idx2; float2* wb; int* histArr;   // histArr[16][8], plain stores
};
__global__ __launch_bounds__(256) void router_topk(FinArgs a) {
  const int tid = threadIdx.x;
  const int lane = tid & 63, wv = tid >> 6;
  const int token = blockIdx.x * 256 + tid;
  float b[8], p[8];
#pragma unroll
  for (int e = 0; e < 8; e++) { b[e] = a.base[token * 8 + e]; p[e] = a.pol[token * 8 + e]; }
  float pm = p[0];
#pragma unroll
  for (int e = 1; e < 8; e++) pm = fmaxf(pm, p[e]);
  float pe[8], psum = 0.f;
#pragma unroll
  for (int e = 0; e < 8; e++) { pe[e] = expf(p[e] - pm); psum += pe[e]; }
  const float pinv = 1.f / psum;
  float sl[8];
#pragma unroll
  for (int e = 0; e < 8; e++) sl[e] = (b[e] + pe[e] * pinv) * 0.5f;
  float sm = sl[0];
#pragma unroll
  for (int e = 1; e < 8; e++) sm = fmaxf(sm, sl[e]);
  float sc[8], ssum = 0.f;
#pragma unroll
  for (int e = 0; e < 8; e++) { sc[e] = expf(sl[e] - sm); ssum += sc[e]; }
  const float sinv = 1.f / ssum;
  float ent = 0.f;
#pragma unroll
  for (int e = 0; e < 8; e++) { float v = sc[e] * sinv; sc[e] = v; ent -= v * logf(v + 1e-6f); }
  float bm = b[0];
#pragma unroll
  for (int e = 1; e < 8; e++) bm = fmaxf(bm, b[e]);
  float zs = 0.f;
#pragma unroll
  for (int e = 0; e < 8; e++) zs += expf(b[e] - bm);
  const float lse = logf(zs) + bm;
  const float zt = lse * lse;
  float m1 = -1e30f, m2 = -1e30f; int i1 = 0, i2 = 0;
#pragma unroll
  for (int e = 0; e < 8; e++) {
    float v = sc[e];
    if (v > m1) { m2 = m1; i2 = i1; m1 = v; i1 = e; }
    else if (v > m2) { m2 = v; i2 = e; }
  }
  a.idx2[token] = i1 | (i2 << 8);
  a.wb[token] = make_float2(m1, m2);

  __shared__ int hist[8];
  if (tid < 8) hist[tid] = 0;
  __syncthreads();
  atomicAdd(&hist[i1], 1);
  atomicAdd(&hist[i2], 1);
  __syncthreads();
  if (tid < 8) a.histArr[blockIdx.x * 8 + tid] = hist[tid];

  // wave-shuffle partials reduction (10 values)
  float vals[10];
  vals[0] = ent; vals[1] = zt;
#pragma unroll
  for (int e = 0; e < 8; e++) vals[2 + e] = 0.f;
  vals[2 + i1] = m1; vals[2 + i2] = m2;
#pragma unroll
  for (int v = 0; v < 10; v++)
#pragma unroll
    for (int off = 32; off > 0; off >>= 1) vals[v] += __shfl_down(vals[v], off);
  __shared__ float wred[4][10];
  if (lane == 0)
#pragma unroll
    for (int v = 0; v < 10; v++) wred[wv][v] = vals[v];
  __syncthreads();
  if (tid < 10)
    a.partials[blockIdx.x * 10 + tid] = wred[0][tid] + wred[1][tid] + wred[2][tid] + wred[3][tid];
}

// ---------------- compaction + setup + losses in one launch (9 blocks) ----------------
__global__ __launch_bounds__(256) void compact_setup(const int* idx2, const int* histArr,
                                                     int2* blkmap, int* nbrow, int* tokmap,
                                                     int* posb, const float* partials, float* tail) {
  const int e = blockIdx.x;
  const int tid = threadIdx.x;
  int cntl[8];
#pragma unroll
  for (int i = 0; i < 8; i++) {
    int s = 0;
    for (int bblk = 0; bblk < 16; bblk++) s += histArr[bblk * 8 + i];
    cntl[i] = s;
  }
  if (e == 8) {
    if (tid == 0) {
      int o = 0, nb = 16;
      for (int i = 0; i < 16; i++) blkmap[i] = make_int2(8, i * 256);
      for (int ex = 0; ex < 8; ex++) {
        const int nbe = (cntl[ex] + 255) >> 8;
        for (int i = 0; i < nbe; i++) blkmap[nb++] = make_int2(ex, 4096 + o + i * 256);
        o += nbe << 8;
      }
      nbrow[0] = nb;
    } else if (tid == 64) {
      float ent = 0.f, z = 0.f, us[8] = {0,0,0,0,0,0,0,0};
      for (int i = 0; i < 16; i++) {
        ent += partials[i * 10 + 0];
        z += partials[i * 10 + 1];
        for (int ex = 0; ex < 8; ex++) us[ex] += partials[i * 10 + 2 + ex];
      }
      float tot = 0.f;
      for (int ex = 0; ex < 8; ex++) tot += us[ex];
      const float meanu = tot / 8.f;
      float uf[8], mu = 0.f;
      for (int ex = 0; ex < 8; ex++) { uf[ex] = us[ex] / (meanu + 1e-6f); mu += uf[ex]; }
      mu /= 8.f;
      float var = 0.f;
      for (int ex = 0; ex < 8; ex++) { float d = uf[ex] - mu; var += d * d; }
      var /= 7.f;
      const float bl = 0.3f * var - 0.1f * (ent / 4096.f) + 1e-4f * (z / 4096.f);
      for (int ex = 0; ex < 8; ex++) tail[ex] = us[ex];
      tail[8] = bl; tail[9] = 0.f; tail[10] = 0.f;
    }
    for (int t = tid; t < 4096; t += 256) tokmap[t] = t;
    return;
  }
  const int lane = tid & 63, wv = tid >> 6;
  __shared__ int wtot[4];
  __shared__ int carry;
  if (tid == 0) carry = 0;
  __syncthreads();
  int off = 0;
  for (int i = 0; i < e; i++) off += ((cntl[i] + 255) >> 8) << 8;
  const int base = 4096 + off;
  for (int c = 0; c < 16; c++) {
    const int t = c * 256 + tid;
    const int ii = idx2[t];
    const int i1 = ii & 255, i2 = ii >> 8;
    const int flag = (i1 == e || i2 == e) ? 1 : 0;
    const unsigned long long m = __ballot(flag);
    const int pre = __popcll(m & ((1ull << lane) - 1ull));
    if (lane == 63) wtot[wv] = pre + flag;
    __syncthreads();
    int wbase = 0;
    for (int i = 0; i < wv; i++) wbase += wtot[i];
    if (flag) {
      const int row = base + carry + wbase + pre;
      tokmap[row] = t;
      posb[t * 2 + (i2 == e ? 1 : 0)] = row;
    }
    __syncthreads();
    if (tid == 0) carry += wtot[0] + wtot[1] + wtot[2] + wtot[3];
    __syncthreads();
  }
  const int ce = cntl[e];
  const int pend = ((ce + 255) >> 8) << 8;
  for (int r = ce + tid; r < pend; r += 256) tokmap[base + r] = 0;
}

// ---------------- combine: out[t] = y2c[t] + w1*y2c[p1] + w2*y2c[p2] ----------------
__global__ __launch_bounds__(256) void combine_g(const u16* y2c, const int* posb,
                                                 const float2* wb, float* out) {
  const int t = blockIdx.x;
  const int c = threadIdx.x;
  const float2 w = wb[t];
  const int p1 = posb[t * 2], p2 = posb[t * 2 + 1];
  ushort4 s = ((const ushort4*)(y2c + (size_t)t * 1024))[c];
  ushort4 a = ((const ushort4*)(y2c + (size_t)p1 * 1024))[c];
  ushort4 b = ((const ushort4*)(y2c + (size_t)p2 * 1024))[c];
  float4 o;
  o.x = bf2f(s.x) + w.x * bf2f(a.x) + w.y * bf2f(b.x);
  o.y = bf2f(s.y) + w.x * bf2f(a.y) + w.y * bf2f(b.y);
  o.z = bf2f(s.z) + w.x * bf2f(a.z) + w.y * bf2f(b.z);
  o.w = bf2f(s.w) + w.x * bf2f(a.w) + w.y * bf2f(b.w);
  ((float4*)(out + (size_t)t * 1024))[c] = o;
}

// ---------------- host ----------------
extern "C" void kernel_launch(void* const* d_in, const int* in_sizes, int n_in,
                              void* d_out, int out_size, void* d_ws, size_t ws_size,
                              hipStream_t stream) {
  const float* x = (const float*)d_in[0];
  const float* scorer_w = (const float*)d_in[1];
  const float* scorer_b = (const float*)d_in[2];
  const float* p1_w = (const float*)d_in[3];
  const float* p1_b = (const float*)d_in[4];
  const float* p2_w = (const float*)d_in[5];
  const float* p2_b = (const float*)d_in[6];
  const float* ew1_w = (const float*)d_in[7];
  const float* ew1_a = (const float*)d_in[8];
  const float* ew1_b = (const float*)d_in[9];
  const float* ew2_w = (const float*)d_in[10];
  const float* ew2_a = (const float*)d_in[11];
  const float* ew2_b = (const float*)d_in[12];
  const float* ew3_w = (const float*)d_in[13];
  const float* ew3_a = (const float*)d_in[14];
  const float* ew3_b = (const float*)d_in[15];
  const float* s1_w = (const float*)d_in[16];
  const float* s1_a = (const float*)d_in[17];
  const float* s1_b = (const float*)d_in[18];
  const float* s2_w = (const float*)d_in[19];
  const float* s2_a = (const float*)d_in[20];
  const float* s2_b = (const float*)d_in[21];
  const float* s3_w = (const float*)d_in[22];
  const float* s3_a = (const float*)d_in[23];
  const float* s3_b = (const float*)d_in[24];
  float* outf = (float*)d_out;

  char* w = (char*)d_ws;
  auto alloc = [&](size_t bytes) { char* p = w; w += (bytes + 255) & ~(size_t)255; return p; };
  u16* xfb  = (u16*)alloc((size_t)TTOK * DDIM * 2);
  u16* ph   = (u16*)alloc((size_t)TTOK * HDIM * 2);
  u16* p1wb = (u16*)alloc((size_t)HDIM * DDIM * 2);
  u16* Adst = (u16*)alloc((size_t)1179648 * 2);
  u16* Bdst = (u16*)alloc((size_t)1474560 * 2);
  u16* Wraw = (u16*)alloc((size_t)27 * 524288 * 2);
  u16* W13  = (u16*)alloc((size_t)9 * 1024 * 1024 * 2);
  u16* W2e  = (u16*)alloc((size_t)9 * 1024 * 512 * 2);
  u16* h2c  = (u16*)alloc((size_t)CROWS * FDIM * 2);
  u16* y2c  = (u16*)alloc((size_t)CROWS * DDIM * 2);
  float* base = (float*)alloc((size_t)TTOK * 8 * 4);
  float* pol  = (float*)alloc((size_t)TTOK * 8 * 4);
  float* partials = (float*)alloc(16 * 10 * 4);
  float* amaxP = (float*)alloc(27 * 128 * 4);
  int* histArr = (int*)alloc(16 * 8 * 4);
  int2* blkmap = (int2*)alloc(64 * 8);
  int* nbrow  = (int*)alloc(4);
  int* tokmap = (int*)alloc(CROWS * 4);
  int* posb   = (int*)alloc(TTOK * 2 * 4);
  int* idx2   = (int*)alloc(TTOK * 4);
  float2* wb  = (float2*)alloc(TTOK * 8);

  // 1. prep: W amax partials + W->bf16 + all conversions (range-partitioned)
  {
    PrepArgs a{};
    for (int e = 0; e < 8; e++) {
      a.W[e] = ew1_w + (size_t)e * 524288;
      a.W[8 + e] = ew3_w + (size_t)e * 524288;
      a.W[18 + e] = ew2_w + (size_t)e * 524288;
      a.Asrc[e] = ew1_a + (size_t)e * 32768;
      a.Asrc[8 + e] = ew3_a + (size_t)e * 32768;
      a.Asrc[18 + e] = ew2_a + (size_t)e * 65536;
      a.Bsrc[e] = ew1_b + (size_t)e * 65536;
      a.Bsrc[8 + e] = ew3_b + (size_t)e * 65536;
      a.Bsrc[18 + e] = ew2_b + (size_t)e * 32768;
    }
    a.W[16] = s1_w; a.W[17] = s3_w; a.W[26] = s2_w;
    a.Asrc[16] = s1_a; a.Asrc[17] = s3_a; a.Asrc[26] = s2_a;
    a.Bsrc[16] = s1_b; a.Bsrc[17] = s3_b; a.Bsrc[26] = s2_b;
    a.Wraw = Wraw; a.amaxP = amaxP;
    a.xf = x; a.xfb = xfb; a.p1w = p1_w; a.p1wb = p1wb;
    a.Adst = Adst; a.Bdst = Bdst;
    hipLaunchKernelGGL(prep_kernel, dim3(7552), dim3(256), 0, stream, a);
  }
  // 2. mid: router hidden gemm64 + merged LoRA fold
  {
    MidArgs g{};
    g.A64 = xfb; g.B64 = p1wb; g.C64 = ph; g.bias64 = p1_b;
    g.A0 = Adst; g.B0 = Bdst; g.Wb = Wraw; g.C13 = W13; g.C2e = W2e; g.amaxP = amaxP;
    hipLaunchKernelGGL(mid_kernel, dim3(1984), dim3(256), 0, stream, g);
  }
  // 3. router small
  {
    RouterArgs r{};
    r.xf = x; r.ph = ph; r.sw = scorer_w; r.sb = scorer_b;
    r.p2w = p2_w; r.p2b = p2_b; r.base = base; r.pol = pol;
    hipLaunchKernelGGL(router_small, dim3(256), dim3(256), 0, stream, r);
  }
  // 4. router topk + per-block counts
  {
    FinArgs f{base, pol, partials, idx2, wb, histArr};
    hipLaunchKernelGGL(router_topk, dim3(16), dim3(256), 0, stream, f);
  }
  // 5. compaction + setup + losses (9 blocks)
  hipLaunchKernelGGL(compact_setup, dim3(9), dim3(256), 0, stream,
                     idx2, histArr, blkmap, nbrow, tokmap, posb, partials,
                     outf + (size_t)TTOK * DDIM);
  // 6. y13 + fused h2 over gathered rows
  {
    GemmGArgs g{xfb, W13, h2c, tokmap, blkmap, nbrow};
    hipLaunchKernelGGL(gemm256g<1>, dim3(56, 4), dim3(512), 0, stream, g);
  }
  // 7. y2 over concat rows
  {
    GemmGArgs g{h2c, W2e, y2c, tokmap, blkmap, nbrow};
    hipLaunchKernelGGL(gemm256g<0>, dim3(56, 4), dim3(512), 0, stream, g);
  }
  // 8. deterministic combine
  hipLaunchKernelGGL(combine_g, dim3(4096), dim3(256), 0, stream, y2c, posb, wb, outf);
}